// Round 2
// baseline (550.371 us; speedup 1.0000x reference)
//
#include <hip/hip_runtime.h>
#include <hip/hip_bf16.h>

typedef __attribute__((ext_vector_type(8))) short short8;
typedef __attribute__((ext_vector_type(4))) float f32x4;

__device__ __forceinline__ short bf16r(float f) {
    union { float f; unsigned u; } v; v.f = f;
    unsigned u = (v.u + 0x7fffu + ((v.u >> 16) & 1u)) >> 16;
    return (short)u;
}
__device__ __forceinline__ float bf2f(short s) {
    union { unsigned u; float f; } v; v.u = ((unsigned)(unsigned short)s) << 16;
    return v.f;
}

#define M_ROWS 32768
#define KP_A 544      // padded K for stage-a GEMMs (524 or 513 real)
#define NF 512

// latent (32768 x 512 f32) -> A[:, 0:512] bf16, row stride 544
__global__ __launch_bounds__(256) void k_latent(const float* __restrict__ latent,
                                                short* __restrict__ A) {
    int idx = blockIdx.x * 256 + threadIdx.x;   // one thread per 8 elements
    int row = idx >> 6;
    int c = (idx & 63) << 3;
    const float* src = latent + (long)row * NF + c;
    float4 f0 = *(const float4*)src;
    float4 f1 = *(const float4*)(src + 4);
    short8 o;
    o[0] = bf16r(f0.x); o[1] = bf16r(f0.y); o[2] = bf16r(f0.z); o[3] = bf16r(f0.w);
    o[4] = bf16r(f1.x); o[5] = bf16r(f1.y); o[6] = bf16r(f1.z); o[7] = bf16r(f1.w);
    *(short8*)(A + (long)row * KP_A + c) = o;
}

// W (din x 512 f32) -> Wt[n][k] bf16 (512 x Kp), zero-pad k>=din
__global__ __launch_bounds__(256) void k_wt(const float* __restrict__ W,
                                            short* __restrict__ Wt, int din, int Kp) {
    int idx = blockIdx.x * 256 + threadIdx.x;
    if (idx >= NF * Kp) return;
    int n = idx / Kp, k = idx - n * Kp;
    Wt[idx] = (k < din) ? bf16r(W[(long)k * NF + n]) : (short)0;
}

// per-batch kNN (top-2, exact reference distance formula) + cov features ->
// A[:, 512:544] (12 real features + zero pad)
__global__ __launch_bounds__(256) void k_knncov(const float* __restrict__ pc,
                                                short* __restrict__ A) {
    __shared__ float sx[2048], sy[2048], sz[2048], sq[2048];
    int b = blockIdx.x >> 3;
    int chunk = blockIdx.x & 7;
    const float* p = pc + (long)b * 2048 * 3;
    for (int i = threadIdx.x; i < 2048; i += 256) {
        float x = p[3 * i], y = p[3 * i + 1], z = p[3 * i + 2];
        sx[i] = x; sy[i] = y; sz[i] = z;
        sq[i] = x * x + y * y + z * z;
    }
    __syncthreads();
    int n = chunk * 256 + threadIdx.x;
    float xn = sx[n], yn = sy[n], zn = sz[n], qn = sq[n];
    float best0 = -INFINITY, best1 = -INFINITY;
    int i0 = 0, i1 = 0;
    for (int m = 0; m < 2048; ++m) {
        float inner = xn * sx[m] + yn * sy[m] + zn * sz[m];
        float negd = -((qn - 2.0f * inner) + sq[m]);
        if (negd > best0) { best1 = best0; i1 = i0; best0 = negd; i0 = m; }
        else if (negd > best1) { best1 = negd; i1 = m; }
    }
    float a0 = sx[i0], a1 = sy[i0], a2 = sz[i0];
    float b0 = sx[i1], b1 = sy[i1], b2 = sz[i1];
    long row = (long)b * 2048 + n;
    short vals[32];
    vals[0] = bf16r(xn); vals[1] = bf16r(yn); vals[2] = bf16r(zn);
    float ou[9] = {a0 * b0, a0 * b1, a0 * b2,
                   a1 * b0, a1 * b1, a1 * b2,
                   a2 * b0, a2 * b1, a2 * b2};
    #pragma unroll
    for (int i = 0; i < 9; ++i) vals[3 + i] = bf16r(ou[i]);
    #pragma unroll
    for (int i = 12; i < 32; ++i) vals[i] = 0;
    short* dst = A + row * KP_A + NF;
    #pragma unroll
    for (int i = 0; i < 4; ++i)
        *(short8*)(dst + i * 8) = *(short8*)(vals + i * 8);
}

// stage 2/3: A[:, 512] = bf16(out), A[:, 513:544] = 0
__global__ __launch_bounds__(256) void k_packout(const float* __restrict__ out,
                                                 short* __restrict__ A) {
    int row = blockIdx.x * 256 + threadIdx.x;
    short vals[32];
    vals[0] = bf16r(out[row]);
    #pragma unroll
    for (int i = 1; i < 32; ++i) vals[i] = 0;
    short* dst = A + (long)row * KP_A + NF;
    #pragma unroll
    for (int i = 0; i < 4; ++i)
        *(short8*)(dst + i * 8) = *(short8*)(vals + i * 8);
}

// C = relu(A @ Bt^T + bias [+ Res]), bf16 in/out, f32 accum.
// A: M x Kp row-major (stride Kp); Bt: N x Kp row-major (pre-transposed weights);
// C: M x 512; Res: M x 512 or null.
#define BM 128
#define BN 128
#define BK 32
#define LDT 40   // padded LDS stride (shorts): 80B, 16B-aligned, ~2-way banks

__global__ __launch_bounds__(256) void k_gemm(const short* __restrict__ A,
                                              const short* __restrict__ Bt,
                                              const float* __restrict__ bias,
                                              const short* __restrict__ Res,
                                              short* __restrict__ C,
                                              int Kp) {
    __shared__ __align__(16) short As[BM * LDT];
    __shared__ __align__(16) short Bs[BN * LDT];
    int bm = blockIdx.x;
    int bn = blockIdx.y;
    int t = threadIdx.x;
    int lane = t & 63, wid = t >> 6;
    int wm = wid >> 1, wn = wid & 1;
    f32x4 acc[4][4] = {};
    const long arow0 = (long)bm * BM;
    const long brow0 = (long)bn * BN;
    int l15 = lane & 15, kq = (lane >> 4) * 8;

    for (int kt = 0; kt < Kp; kt += BK) {
        #pragma unroll
        for (int p = 0; p < 2; ++p) {
            int r = p * 64 + (t >> 2);
            int k0 = (t & 3) * 8;
            *(short8*)&As[r * LDT + k0] = *(const short8*)&A[(arow0 + r) * Kp + kt + k0];
            *(short8*)&Bs[r * LDT + k0] = *(const short8*)&Bt[(brow0 + r) * Kp + kt + k0];
        }
        __syncthreads();
        short8 fa[4], fb[4];
        #pragma unroll
        for (int i = 0; i < 4; ++i) {
            fa[i] = *(const short8*)&As[(wm * 64 + i * 16 + l15) * LDT + kq];
            fb[i] = *(const short8*)&Bs[(wn * 64 + i * 16 + l15) * LDT + kq];
        }
        #pragma unroll
        for (int i = 0; i < 4; ++i)
            #pragma unroll
            for (int j = 0; j < 4; ++j)
                acc[i][j] = __builtin_amdgcn_mfma_f32_16x16x32_bf16(fa[i], fb[j], acc[i][j], 0, 0, 0);
        __syncthreads();
    }

    int rq = (lane >> 4) * 4;
    #pragma unroll
    for (int i = 0; i < 4; ++i) {
        #pragma unroll
        for (int j = 0; j < 4; ++j) {
            int col = bn * BN + wn * 64 + j * 16 + l15;
            float bval = bias[col];
            #pragma unroll
            for (int r = 0; r < 4; ++r) {
                long row = arow0 + wm * 64 + i * 16 + rq + r;
                float v = acc[i][j][r] + bval;
                if (Res) v += bf2f(Res[row * NF + col]);
                v = fmaxf(v, 0.0f);
                C[row * NF + col] = bf16r(v);
            }
        }
    }
}

// out[row] (+)= dot(H[row, :512], wo) + bo   (one wave per row, 4 rows/block)
__global__ __launch_bounds__(256) void k_gemv(const short* __restrict__ H,
                                              const float* __restrict__ wo,
                                              const float* __restrict__ bo,
                                              float* __restrict__ out, int add) {
    int wave = (blockIdx.x << 2) | (threadIdx.x >> 6);
    int lane = threadIdx.x & 63;
    const short* h = H + (long)wave * NF + lane * 8;
    short8 hv = *(const short8*)h;
    const float* w = wo + lane * 8;
    float s = 0.0f;
    #pragma unroll
    for (int i = 0; i < 8; ++i) s += bf2f(hv[i]) * w[i];
    #pragma unroll
    for (int off = 32; off; off >>= 1) s += __shfl_xor(s, off, 64);
    if (lane == 0) {
        float v = s + bo[0];
        out[wave] = add ? (out[wave] + v) : v;
    }
}

extern "C" void kernel_launch(void* const* d_in, const int* in_sizes, int n_in,
                              void* d_out, int out_size, void* d_ws, size_t ws_size,
                              hipStream_t stream) {
    (void)in_sizes; (void)n_in; (void)out_size; (void)ws_size;
    const float* latent = (const float*)d_in[0];
    const float* pc     = (const float*)d_in[1];
    const float *wa[3], *ba[3], *wr[3], *br[3], *wo[3], *bo[3];
    for (int s = 0; s < 3; ++s) {
        int base = 2 + s * 6;
        wa[s] = (const float*)d_in[base + 0];
        ba[s] = (const float*)d_in[base + 1];
        wr[s] = (const float*)d_in[base + 2];
        br[s] = (const float*)d_in[base + 3];
        wo[s] = (const float*)d_in[base + 4];
        bo[s] = (const float*)d_in[base + 5];
    }

    char* ws = (char*)d_ws;
    size_t off = 0;
    short* A  = (short*)(ws + off); off += (size_t)M_ROWS * KP_A * 2;
    short* H1 = (short*)(ws + off); off += (size_t)M_ROWS * NF * 2;
    short* H2 = (short*)(ws + off); off += (size_t)M_ROWS * NF * 2;
    short *Wta[3], *Wtr[3];
    for (int s = 0; s < 3; ++s) {
        Wta[s] = (short*)(ws + off); off += (size_t)NF * KP_A * 2;
        Wtr[s] = (short*)(ws + off); off += (size_t)NF * NF * 2;
    }
    float* out = (float*)d_out;

    k_latent<<<(M_ROWS * 64) / 256, 256, 0, stream>>>(latent, A);
    for (int s = 0; s < 3; ++s) {
        int din_a = (s == 0) ? 524 : 513;
        k_wt<<<(NF * KP_A + 255) / 256, 256, 0, stream>>>(wa[s], Wta[s], din_a, KP_A);
        k_wt<<<(NF * NF + 255) / 256, 256, 0, stream>>>(wr[s], Wtr[s], NF, NF);
    }
    k_knncov<<<128, 256, 0, stream>>>(pc, A);

    dim3 gg(M_ROWS / BM, NF / BN);
    for (int s = 0; s < 3; ++s) {
        if (s > 0) k_packout<<<M_ROWS / 256, 256, 0, stream>>>(out, A);
        k_gemm<<<gg, 256, 0, stream>>>(A,  Wta[s], ba[s], nullptr, H1, KP_A);
        k_gemm<<<gg, 256, 0, stream>>>(H1, Wtr[s], br[s], H1,      H2, NF);
        k_gemv<<<M_ROWS / 4, 256, 0, stream>>>(H2, wo[s], bo[s], out, s > 0 ? 1 : 0);
    }
}

// Round 4
// 381.816 us; speedup vs baseline: 1.4415x; 1.4415x over previous
//
#include <hip/hip_runtime.h>
#include <hip/hip_bf16.h>

typedef __attribute__((ext_vector_type(8))) short short8;
typedef __attribute__((ext_vector_type(4))) float f32x4;

__device__ __forceinline__ short bf16r(float f) {
    union { float f; unsigned u; } v; v.f = f;
    unsigned u = (v.u + 0x7fffu + ((v.u >> 16) & 1u)) >> 16;
    return (short)u;
}
__device__ __forceinline__ float bf2f(short s) {
    union { unsigned u; float f; } v; v.u = ((unsigned)(unsigned short)s) << 16;
    return v.f;
}

#define M_ROWS 32768
#define KP_A 544      // padded K for stage-a GEMMs (524 or 513 real)
#define NF 512

// latent (32768 x 512 f32) -> A[:, 0:512] bf16, row stride 544
__global__ __launch_bounds__(256) void k_latent(const float* __restrict__ latent,
                                                short* __restrict__ A) {
    int idx = blockIdx.x * 256 + threadIdx.x;   // one thread per 8 elements
    int row = idx >> 6;
    int c = (idx & 63) << 3;
    const float* src = latent + (long)row * NF + c;
    float4 f0 = *(const float4*)src;
    float4 f1 = *(const float4*)(src + 4);
    short8 o;
    o[0] = bf16r(f0.x); o[1] = bf16r(f0.y); o[2] = bf16r(f0.z); o[3] = bf16r(f0.w);
    o[4] = bf16r(f1.x); o[5] = bf16r(f1.y); o[6] = bf16r(f1.z); o[7] = bf16r(f1.w);
    *(short8*)(A + (long)row * KP_A + c) = o;
}

// W (din x 512 f32) -> Wt[n][k] bf16 (512 x Kp), zero-pad k>=din.
// 32x32 LDS-tile transpose, coalesced read (along n) and write (along k).
__global__ __launch_bounds__(256) void k_wt(const float* __restrict__ W,
                                            short* __restrict__ Wt, int din, int Kp) {
    __shared__ float tile[32][33];
    int kt = blockIdx.x * 32;
    int nt = blockIdx.y * 32;
    int tx = threadIdx.x & 31, ty = threadIdx.x >> 5;   // 32 x 8
    #pragma unroll
    for (int r = 0; r < 32; r += 8) {
        int k = kt + ty + r;
        tile[ty + r][tx] = (k < din) ? W[(long)k * NF + nt + tx] : 0.0f;
    }
    __syncthreads();
    #pragma unroll
    for (int r = 0; r < 32; r += 8) {
        int n = nt + ty + r, k = kt + tx;
        if (k < Kp) Wt[(long)n * Kp + k] = bf16r(tile[tx][ty + r]);
    }
}

__device__ __forceinline__ bool beats(float va, int ia, float vb, int ib) {
    return va > vb || (va == vb && ia < ib);
}

// per-batch kNN (top-2, exact reference distance formula) + cov features ->
// A[:, 512:544]. Grid: 16 batches x 64 chunks; block = 4 waves, 8 queries/wave.
// Phase 1: wave-parallel scan + butterfly merge -> LDS. Phase 2 (uniform,
// after block barrier): 32 threads compute cov + write A.
__global__ __launch_bounds__(256) void k_knncov(const float* __restrict__ pc,
                                                short* __restrict__ A) {
    __shared__ float sx[2048], sy[2048], sz[2048], sq[2048];
    __shared__ int ires[64];          // [wid*16 + i*2 + {0,1}]
    int b = blockIdx.x >> 6;
    int chunk = blockIdx.x & 63;      // 32 queries per block
    const float* p = pc + (long)b * 2048 * 3;
    for (int i = threadIdx.x; i < 2048; i += 256) {
        float x = p[3 * i], y = p[3 * i + 1], z = p[3 * i + 2];
        sx[i] = x; sy[i] = y; sz[i] = z;
        sq[i] = x * x + y * y + z * z;
    }
    __syncthreads();
    int wid = threadIdx.x >> 6, lane = threadIdx.x & 63;
    int nbase = chunk * 32 + wid * 8;

    float qx[8], qy[8], qz[8], qq[8];
    #pragma unroll
    for (int i = 0; i < 8; ++i) {
        qx[i] = sx[nbase + i]; qy[i] = sy[nbase + i];
        qz[i] = sz[nbase + i]; qq[i] = sq[nbase + i];
    }
    float b0[8], b1[8]; int j0[8], j1[8];
    #pragma unroll
    for (int i = 0; i < 8; ++i) { b0[i] = -INFINITY; b1[i] = -INFINITY; j0[i] = 0; j1[i] = 0; }

    for (int it = 0; it < 32; ++it) {
        int m = it * 64 + lane;
        float mx = sx[m], my = sy[m], mz = sz[m], mq = sq[m];
        #pragma unroll
        for (int i = 0; i < 8; ++i) {
            float inner = qx[i] * mx + qy[i] * my + qz[i] * mz;
            float negd = -((qq[i] - 2.0f * inner) + mq);
            if (negd > b0[i]) { b1[i] = b0[i]; j1[i] = j0[i]; b0[i] = negd; j0[i] = m; }
            else if (negd > b1[i]) { b1[i] = negd; j1[i] = m; }
        }
    }

    #pragma unroll
    for (int i = 0; i < 8; ++i) {
        float v0 = b0[i], v1 = b1[i]; int k0 = j0[i], k1 = j1[i];
        #pragma unroll
        for (int off = 1; off < 64; off <<= 1) {
            float w0 = __shfl_xor(v0, off, 64), w1 = __shfl_xor(v1, off, 64);
            int   l0 = __shfl_xor(k0, off, 64), l1 = __shfl_xor(k1, off, 64);
            float n0v, n1v; int n0i, n1i;
            if (beats(v0, k0, w0, l0)) {
                n0v = v0; n0i = k0;
                if (beats(w0, l0, v1, k1)) { n1v = w0; n1i = l0; } else { n1v = v1; n1i = k1; }
            } else {
                n0v = w0; n0i = l0;
                if (beats(v0, k0, w1, l1)) { n1v = v0; n1i = k0; } else { n1v = w1; n1i = l1; }
            }
            v0 = n0v; k0 = n0i; v1 = n1v; k1 = n1i;
        }
        if (lane == 0) {
            ires[wid * 16 + i * 2]     = k0;
            ires[wid * 16 + i * 2 + 1] = k1;
        }
    }
    __syncthreads();
    if (threadIdx.x < 32) {
        int t = threadIdx.x;
        int k0 = ires[(t >> 3) * 16 + (t & 7) * 2];
        int k1 = ires[(t >> 3) * 16 + (t & 7) * 2 + 1];
        int n = chunk * 32 + t;
        float xn = sx[n], yn = sy[n], zn = sz[n];
        float a0 = sx[k0], a1 = sy[k0], a2 = sz[k0];
        float c0 = sx[k1], c1 = sy[k1], c2 = sz[k1];
        long row = (long)b * 2048 + n;
        short vals[32];
        vals[0] = bf16r(xn); vals[1] = bf16r(yn); vals[2] = bf16r(zn);
        float ou[9] = {a0 * c0, a0 * c1, a0 * c2,
                       a1 * c0, a1 * c1, a1 * c2,
                       a2 * c0, a2 * c1, a2 * c2};
        #pragma unroll
        for (int q = 0; q < 9; ++q) vals[3 + q] = bf16r(ou[q]);
        #pragma unroll
        for (int q = 12; q < 32; ++q) vals[q] = 0;
        short* dst = A + row * KP_A + NF;
        #pragma unroll
        for (int q = 0; q < 4; ++q)
            *(short8*)(dst + q * 8) = *(short8*)(vals + q * 8);
    }
}

// stage 2/3: A[:, 512] = bf16(out), A[:, 513:544] = 0
__global__ __launch_bounds__(256) void k_packout(const float* __restrict__ out,
                                                 short* __restrict__ A) {
    int row = blockIdx.x * 256 + threadIdx.x;
    short vals[32];
    vals[0] = bf16r(out[row]);
    #pragma unroll
    for (int i = 1; i < 32; ++i) vals[i] = 0;
    short* dst = A + (long)row * KP_A + NF;
    #pragma unroll
    for (int i = 0; i < 4; ++i)
        *(short8*)(dst + i * 8) = *(short8*)(vals + i * 8);
}

// out = bo (add=0) or out += bo (add=1)
__global__ __launch_bounds__(256) void k_setbo(float* __restrict__ out,
                                               const float* __restrict__ bo, int add) {
    int i = blockIdx.x * 256 + threadIdx.x;
    float v = bo[0];
    out[i] = add ? (out[i] + v) : v;
}

// GEMM, two epilogues:
//  wov == null: C = relu(A @ Bt^T + bias [+ Res])  (bf16 store)
//  wov != null: fused gemv — out[row] += sum_col relu(...)*wov[col] via
//               16-lane shfl reduce + one atomicAdd per (row, wave).
#define BM 128
#define BN 128
#define BK 32
#define LDT 40   // padded LDS stride (shorts): 80B, 16B-aligned, ~2-way banks

__global__ __launch_bounds__(256) void k_gemm(const short* __restrict__ A,
                                              const short* __restrict__ Bt,
                                              const float* __restrict__ bias,
                                              const short* __restrict__ Res,
                                              short* __restrict__ C,
                                              const float* __restrict__ wov,
                                              float* __restrict__ outp,
                                              int Kp) {
    __shared__ __align__(16) short As[BM * LDT];
    __shared__ __align__(16) short Bs[BN * LDT];
    int bm = blockIdx.x;
    int bn = blockIdx.y;
    int t = threadIdx.x;
    int lane = t & 63, wid = t >> 6;
    int wm = wid >> 1, wn = wid & 1;
    f32x4 acc[4][4] = {};
    const long arow0 = (long)bm * BM;
    const long brow0 = (long)bn * BN;
    int l15 = lane & 15, kq = (lane >> 4) * 8;

    for (int kt = 0; kt < Kp; kt += BK) {
        #pragma unroll
        for (int p = 0; p < 2; ++p) {
            int r = p * 64 + (t >> 2);
            int k0 = (t & 3) * 8;
            *(short8*)&As[r * LDT + k0] = *(const short8*)&A[(arow0 + r) * Kp + kt + k0];
            *(short8*)&Bs[r * LDT + k0] = *(const short8*)&Bt[(brow0 + r) * Kp + kt + k0];
        }
        __syncthreads();
        short8 fa[4], fb[4];
        #pragma unroll
        for (int i = 0; i < 4; ++i) {
            fa[i] = *(const short8*)&As[(wm * 64 + i * 16 + l15) * LDT + kq];
            fb[i] = *(const short8*)&Bs[(wn * 64 + i * 16 + l15) * LDT + kq];
        }
        #pragma unroll
        for (int i = 0; i < 4; ++i)
            #pragma unroll
            for (int j = 0; j < 4; ++j)
                acc[i][j] = __builtin_amdgcn_mfma_f32_16x16x32_bf16(fa[i], fb[j], acc[i][j], 0, 0, 0);
        __syncthreads();
    }

    int rq4 = (lane >> 4) * 4;
    if (wov == nullptr) {
        #pragma unroll
        for (int i = 0; i < 4; ++i) {
            #pragma unroll
            for (int j = 0; j < 4; ++j) {
                int col = bn * BN + wn * 64 + j * 16 + l15;
                float bval = bias[col];
                #pragma unroll
                for (int r = 0; r < 4; ++r) {
                    long row = arow0 + wm * 64 + i * 16 + rq4 + r;
                    float v = acc[i][j][r] + bval;
                    if (Res) v += bf2f(Res[row * NF + col]);
                    v = fmaxf(v, 0.0f);
                    C[row * NF + col] = bf16r(v);
                }
            }
        }
    } else {
        float wv[4], bv[4];
        #pragma unroll
        for (int j = 0; j < 4; ++j) {
            int col = bn * BN + wn * 64 + j * 16 + l15;
            wv[j] = wov[col];
            bv[j] = bias[col];
        }
        #pragma unroll
        for (int i = 0; i < 4; ++i) {
            #pragma unroll
            for (int r = 0; r < 4; ++r) {
                long row = arow0 + wm * 64 + i * 16 + rq4 + r;
                float s = 0.0f;
                #pragma unroll
                for (int j = 0; j < 4; ++j) {
                    int col = bn * BN + wn * 64 + j * 16 + l15;
                    float v = acc[i][j][r] + bv[j] + bf2f(Res[row * NF + col]);
                    v = fmaxf(v, 0.0f);
                    s += v * wv[j];
                }
                s += __shfl_xor(s, 1, 64);
                s += __shfl_xor(s, 2, 64);
                s += __shfl_xor(s, 4, 64);
                s += __shfl_xor(s, 8, 64);
                if (l15 == 0) atomicAdd(outp + row, s);
            }
        }
    }
}

extern "C" void kernel_launch(void* const* d_in, const int* in_sizes, int n_in,
                              void* d_out, int out_size, void* d_ws, size_t ws_size,
                              hipStream_t stream) {
    (void)in_sizes; (void)n_in; (void)out_size; (void)ws_size;
    const float* latent = (const float*)d_in[0];
    const float* pc     = (const float*)d_in[1];
    const float *wa[3], *ba[3], *wr[3], *br[3], *wo[3], *bo[3];
    for (int s = 0; s < 3; ++s) {
        int base = 2 + s * 6;
        wa[s] = (const float*)d_in[base + 0];
        ba[s] = (const float*)d_in[base + 1];
        wr[s] = (const float*)d_in[base + 2];
        br[s] = (const float*)d_in[base + 3];
        wo[s] = (const float*)d_in[base + 4];
        bo[s] = (const float*)d_in[base + 5];
    }

    char* ws = (char*)d_ws;
    size_t off = 0;
    short* A  = (short*)(ws + off); off += (size_t)M_ROWS * KP_A * 2;   // 35.7 MB
    short* H1 = (short*)(ws + off); off += (size_t)M_ROWS * NF * 2;     // 33.6 MB
    short *Wta[3], *Wtr[3];
    for (int s = 0; s < 3; ++s) {
        Wta[s] = (short*)(ws + off); off += (size_t)NF * KP_A * 2;
        Wtr[s] = (short*)(ws + off); off += (size_t)NF * NF * 2;
    }
    float* out = (float*)d_out;

    k_latent<<<(M_ROWS * 64) / 256, 256, 0, stream>>>(latent, A);
    for (int s = 0; s < 3; ++s) {
        int din_a = (s == 0) ? 524 : 513;
        dim3 ga((KP_A + 31) / 32, NF / 32);
        k_wt<<<ga, 256, 0, stream>>>(wa[s], Wta[s], din_a, KP_A);
        dim3 gr(NF / 32, NF / 32);
        k_wt<<<gr, 256, 0, stream>>>(wr[s], Wtr[s], NF, NF);
    }
    k_knncov<<<1024, 256, 0, stream>>>(pc, A);

    dim3 gg(M_ROWS / BM, NF / BN);
    for (int s = 0; s < 3; ++s) {
        if (s > 0) k_packout<<<M_ROWS / 256, 256, 0, stream>>>(out, A);
        k_setbo<<<M_ROWS / 256, 256, 0, stream>>>(out, bo[s], s > 0 ? 1 : 0);
        k_gemm<<<gg, 256, 0, stream>>>(A,  Wta[s], ba[s], nullptr, H1,
                                       nullptr, nullptr, KP_A);
        k_gemm<<<gg, 256, 0, stream>>>(H1, Wtr[s], br[s], H1, nullptr,
                                       wo[s], out, NF);
    }
}

// Round 5
// 351.257 us; speedup vs baseline: 1.5669x; 1.0870x over previous
//
#include <hip/hip_runtime.h>
#include <hip/hip_bf16.h>

typedef __attribute__((ext_vector_type(8))) short short8;
typedef __attribute__((ext_vector_type(4))) float f32x4;

__device__ __forceinline__ short bf16r(float f) {
    union { float f; unsigned u; } v; v.f = f;
    unsigned u = (v.u + 0x7fffu + ((v.u >> 16) & 1u)) >> 16;
    return (short)u;
}
__device__ __forceinline__ float bf2f(short s) {
    union { unsigned u; float f; } v; v.u = ((unsigned)(unsigned short)s) << 16;
    return v.f;
}

// LDS bank swizzle for [row][32-short] tiles: 16B-slot s -> s ^ fswz(row).
// Involution; applied inverse on the global staging source, forward on ds_read.
__device__ __forceinline__ int fswz(int r) { return (r ^ (r >> 2)) & 3; }

// async global->LDS, 16B per lane; LDS dest = wave-uniform base + lane*16.
__device__ __forceinline__ void gl16(const short* g, short* l) {
    __builtin_amdgcn_global_load_lds(
        (const __attribute__((address_space(1))) unsigned int*)g,
        (__attribute__((address_space(3))) unsigned int*)l, 16, 0, 0);
}

#define M_ROWS 32768
#define KP_A 544      // padded K for stage-a GEMMs (524 or 513 real)
#define NF 512

// latent (32768 x 512 f32) -> A[:, 0:512] bf16, row stride 544
__global__ __launch_bounds__(256) void k_latent(const float* __restrict__ latent,
                                                short* __restrict__ A) {
    int idx = blockIdx.x * 256 + threadIdx.x;   // one thread per 8 elements
    int row = idx >> 6;
    int c = (idx & 63) << 3;
    const float* src = latent + (long)row * NF + c;
    float4 f0 = *(const float4*)src;
    float4 f1 = *(const float4*)(src + 4);
    short8 o;
    o[0] = bf16r(f0.x); o[1] = bf16r(f0.y); o[2] = bf16r(f0.z); o[3] = bf16r(f0.w);
    o[4] = bf16r(f1.x); o[5] = bf16r(f1.y); o[6] = bf16r(f1.z); o[7] = bf16r(f1.w);
    *(short8*)(A + (long)row * KP_A + c) = o;
}

// W (din x 512 f32) -> Wt[n][k] bf16 (512 x Kp), zero-pad k>=din.
__global__ __launch_bounds__(256) void k_wt(const float* __restrict__ W,
                                            short* __restrict__ Wt, int din, int Kp) {
    __shared__ float tile[32][33];
    int kt = blockIdx.x * 32;
    int nt = blockIdx.y * 32;
    int tx = threadIdx.x & 31, ty = threadIdx.x >> 5;   // 32 x 8
    #pragma unroll
    for (int r = 0; r < 32; r += 8) {
        int k = kt + ty + r;
        tile[ty + r][tx] = (k < din) ? W[(long)k * NF + nt + tx] : 0.0f;
    }
    __syncthreads();
    #pragma unroll
    for (int r = 0; r < 32; r += 8) {
        int n = nt + ty + r, k = kt + tx;
        if (k < Kp) Wt[(long)n * Kp + k] = bf16r(tile[tx][ty + r]);
    }
}

__device__ __forceinline__ bool beats(float va, int ia, float vb, int ib) {
    return va > vb || (va == vb && ia < ib);
}

// per-batch kNN (top-2) + cov features -> A[:, 512:544].
// Grid: 16 batches x 128 chunks; block = 4 waves, 4 queries/wave (low VGPR state,
// no spill). 64 lanes scan stride-64, per-lane top-2, butterfly merge -> LDS,
// uniform phase-2 writes A.
__global__ __launch_bounds__(256, 2) void k_knncov(const float* __restrict__ pc,
                                                   short* __restrict__ A) {
    __shared__ float sx[2048], sy[2048], sz[2048], sq[2048];
    __shared__ int ires[32];          // [wid*8 + i*2 + {0,1}]
    int b = blockIdx.x >> 7;
    int chunk = blockIdx.x & 127;     // 16 queries per block
    const float* p = pc + (long)b * 2048 * 3;
    for (int i = threadIdx.x; i < 2048; i += 256) {
        float x = p[3 * i], y = p[3 * i + 1], z = p[3 * i + 2];
        sx[i] = x; sy[i] = y; sz[i] = z;
        sq[i] = x * x + y * y + z * z;
    }
    __syncthreads();
    int wid = threadIdx.x >> 6, lane = threadIdx.x & 63;
    int nbase = chunk * 16 + wid * 4;

    float qx[4], qy[4], qz[4], qq[4];
    #pragma unroll
    for (int i = 0; i < 4; ++i) {
        qx[i] = sx[nbase + i]; qy[i] = sy[nbase + i];
        qz[i] = sz[nbase + i]; qq[i] = sq[nbase + i];
    }
    float b0[4], b1[4]; int j0[4], j1[4];
    #pragma unroll
    for (int i = 0; i < 4; ++i) { b0[i] = -INFINITY; b1[i] = -INFINITY; j0[i] = 0; j1[i] = 0; }

    for (int it = 0; it < 32; ++it) {
        int m = it * 64 + lane;
        float mx = sx[m], my = sy[m], mz = sz[m], mq = sq[m];
        #pragma unroll
        for (int i = 0; i < 4; ++i) {
            float inner = qx[i] * mx + qy[i] * my + qz[i] * mz;
            float negd = -((qq[i] - 2.0f * inner) + mq);
            if (negd > b0[i]) { b1[i] = b0[i]; j1[i] = j0[i]; b0[i] = negd; j0[i] = m; }
            else if (negd > b1[i]) { b1[i] = negd; j1[i] = m; }
        }
    }

    #pragma unroll
    for (int i = 0; i < 4; ++i) {
        float v0 = b0[i], v1 = b1[i]; int k0 = j0[i], k1 = j1[i];
        #pragma unroll
        for (int off = 1; off < 64; off <<= 1) {
            float w0 = __shfl_xor(v0, off, 64), w1 = __shfl_xor(v1, off, 64);
            int   l0 = __shfl_xor(k0, off, 64), l1 = __shfl_xor(k1, off, 64);
            float n0v, n1v; int n0i, n1i;
            if (beats(v0, k0, w0, l0)) {
                n0v = v0; n0i = k0;
                if (beats(w0, l0, v1, k1)) { n1v = w0; n1i = l0; } else { n1v = v1; n1i = k1; }
            } else {
                n0v = w0; n0i = l0;
                if (beats(v0, k0, w1, l1)) { n1v = v0; n1i = k0; } else { n1v = w1; n1i = l1; }
            }
            v0 = n0v; k0 = n0i; v1 = n1v; k1 = n1i;
        }
        if (lane == 0) {
            ires[wid * 8 + i * 2]     = k0;
            ires[wid * 8 + i * 2 + 1] = k1;
        }
    }
    __syncthreads();
    if (threadIdx.x < 16) {
        int t = threadIdx.x;
        int k0 = ires[(t >> 2) * 8 + (t & 3) * 2];
        int k1 = ires[(t >> 2) * 8 + (t & 3) * 2 + 1];
        int n = chunk * 16 + t;
        float xn = sx[n], yn = sy[n], zn = sz[n];
        float a0 = sx[k0], a1 = sy[k0], a2 = sz[k0];
        float c0 = sx[k1], c1 = sy[k1], c2 = sz[k1];
        long row = (long)b * 2048 + n;
        short vals[32];
        vals[0] = bf16r(xn); vals[1] = bf16r(yn); vals[2] = bf16r(zn);
        float ou[9] = {a0 * c0, a0 * c1, a0 * c2,
                       a1 * c0, a1 * c1, a1 * c2,
                       a2 * c0, a2 * c1, a2 * c2};
        #pragma unroll
        for (int q = 0; q < 9; ++q) vals[3 + q] = bf16r(ou[q]);
        #pragma unroll
        for (int q = 12; q < 32; ++q) vals[q] = 0;
        short* dst = A + row * KP_A + NF;
        #pragma unroll
        for (int q = 0; q < 4; ++q)
            *(short8*)(dst + q * 8) = *(short8*)(vals + q * 8);
    }
}

// stage 2/3: A[:, 512] = bf16(out), A[:, 513:544] = 0
__global__ __launch_bounds__(256) void k_packout(const float* __restrict__ out,
                                                 short* __restrict__ A) {
    int row = blockIdx.x * 256 + threadIdx.x;
    short vals[32];
    vals[0] = bf16r(out[row]);
    #pragma unroll
    for (int i = 1; i < 32; ++i) vals[i] = 0;
    short* dst = A + (long)row * KP_A + NF;
    #pragma unroll
    for (int i = 0; i < 4; ++i)
        *(short8*)(dst + i * 8) = *(short8*)(vals + i * 8);
}

// out = bo (add=0) or out += bo (add=1)
__global__ __launch_bounds__(256) void k_setbo(float* __restrict__ out,
                                               const float* __restrict__ bo, int add) {
    int i = blockIdx.x * 256 + threadIdx.x;
    float v = bo[0];
    out[i] = add ? (out[i] + v) : v;
}

// GEMM (m97-structure): 128x128 tile, BK=32, global_load_lds width-16 staging
// into linear [128][32] LDS with XOR-swizzled source/read. Two epilogues:
//  wov == null: C = relu(A @ Bt^T + bias [+ Res])  (bf16 store)
//  wov != null: fused gemv — out[row] += sum_col relu(...)*wov[col].
#define BM 128
#define BN 128
#define BK 32

__global__ __launch_bounds__(256) void k_gemm(const short* __restrict__ A,
                                              const short* __restrict__ Bt,
                                              const float* __restrict__ bias,
                                              const short* __restrict__ Res,
                                              short* __restrict__ C,
                                              const float* __restrict__ wov,
                                              float* __restrict__ outp,
                                              int Kp) {
    __shared__ __align__(16) short As[BM * BK];
    __shared__ __align__(16) short Bs[BN * BK];
    int bm = blockIdx.x, bn = blockIdx.y;
    int t = threadIdx.x, lane = t & 63, wid = t >> 6;
    int wm = wid >> 1, wn = wid & 1;
    f32x4 acc[4][4] = {};
    const long arow0 = (long)bm * BM, brow0 = (long)bn * BN;
    int l15 = lane & 15;

    // staging: wave wid owns 1KB chunks {wid*2, wid*2+1} of As and Bs.
    // chunk c: lane l -> LDS row c*16 + (l>>2), 16B-slot l&3 (linear dest);
    // global source slot = (l&3) ^ fswz(row) so swizzled reads see logical k.
    int rc0 = (wid * 2) * 16 + (lane >> 2);
    int rc1 = (wid * 2 + 1) * 16 + (lane >> 2);
    int ks0 = ((lane & 3) ^ fswz(rc0)) * 8;
    int ks1 = ((lane & 3) ^ fswz(rc1)) * 8;
    long aoff0 = (arow0 + rc0) * (long)Kp + ks0;
    long aoff1 = (arow0 + rc1) * (long)Kp + ks1;
    long boff0 = (brow0 + rc0) * (long)Kp + ks0;
    long boff1 = (brow0 + rc1) * (long)Kp + ks1;
    short* asb0 = As + (wid * 2) * 512;
    short* asb1 = As + (wid * 2 + 1) * 512;
    short* bsb0 = Bs + (wid * 2) * 512;
    short* bsb1 = Bs + (wid * 2 + 1) * 512;

    // fragment read offsets (shorts): logical slot (lane>>4) ^ fswz(row)
    int ra[4], rb[4];
    #pragma unroll
    for (int i = 0; i < 4; ++i) {
        int rA = wm * 64 + i * 16 + l15;
        int rB = wn * 64 + i * 16 + l15;
        ra[i] = rA * 32 + (((lane >> 4) ^ fswz(rA)) * 8);
        rb[i] = rB * 32 + (((lane >> 4) ^ fswz(rB)) * 8);
    }

    for (int kt = 0; kt < Kp; kt += BK) {
        gl16(A + aoff0 + kt, asb0);
        gl16(A + aoff1 + kt, asb1);
        gl16(Bt + boff0 + kt, bsb0);
        gl16(Bt + boff1 + kt, bsb1);
        __syncthreads();
        short8 fa[4], fb[4];
        #pragma unroll
        for (int i = 0; i < 4; ++i) {
            fa[i] = *(const short8*)&As[ra[i]];
            fb[i] = *(const short8*)&Bs[rb[i]];
        }
        #pragma unroll
        for (int i = 0; i < 4; ++i)
            #pragma unroll
            for (int j = 0; j < 4; ++j)
                acc[i][j] = __builtin_amdgcn_mfma_f32_16x16x32_bf16(fa[i], fb[j], acc[i][j], 0, 0, 0);
        __syncthreads();
    }

    int rq4 = (lane >> 4) * 4;
    if (wov == nullptr) {
        #pragma unroll
        for (int i = 0; i < 4; ++i) {
            #pragma unroll
            for (int j = 0; j < 4; ++j) {
                int col = bn * BN + wn * 64 + j * 16 + l15;
                float bval = bias[col];
                #pragma unroll
                for (int r = 0; r < 4; ++r) {
                    long row = arow0 + wm * 64 + i * 16 + rq4 + r;
                    float v = acc[i][j][r] + bval;
                    if (Res) v += bf2f(Res[row * NF + col]);
                    v = fmaxf(v, 0.0f);
                    C[row * NF + col] = bf16r(v);
                }
            }
        }
    } else {
        float wv[4], bv[4];
        #pragma unroll
        for (int j = 0; j < 4; ++j) {
            int col = bn * BN + wn * 64 + j * 16 + l15;
            wv[j] = wov[col];
            bv[j] = bias[col];
        }
        #pragma unroll
        for (int i = 0; i < 4; ++i) {
            #pragma unroll
            for (int r = 0; r < 4; ++r) {
                long row = arow0 + wm * 64 + i * 16 + rq4 + r;
                float s = 0.0f;
                #pragma unroll
                for (int j = 0; j < 4; ++j) {
                    int col = bn * BN + wn * 64 + j * 16 + l15;
                    float v = acc[i][j][r] + bv[j] + bf2f(Res[row * NF + col]);
                    v = fmaxf(v, 0.0f);
                    s += v * wv[j];
                }
                s += __shfl_xor(s, 1, 64);
                s += __shfl_xor(s, 2, 64);
                s += __shfl_xor(s, 4, 64);
                s += __shfl_xor(s, 8, 64);
                if (l15 == 0) atomicAdd(outp + row, s);
            }
        }
    }
}

extern "C" void kernel_launch(void* const* d_in, const int* in_sizes, int n_in,
                              void* d_out, int out_size, void* d_ws, size_t ws_size,
                              hipStream_t stream) {
    (void)in_sizes; (void)n_in; (void)out_size; (void)ws_size;
    const float* latent = (const float*)d_in[0];
    const float* pc     = (const float*)d_in[1];
    const float *wa[3], *ba[3], *wr[3], *br[3], *wo[3], *bo[3];
    for (int s = 0; s < 3; ++s) {
        int base = 2 + s * 6;
        wa[s] = (const float*)d_in[base + 0];
        ba[s] = (const float*)d_in[base + 1];
        wr[s] = (const float*)d_in[base + 2];
        br[s] = (const float*)d_in[base + 3];
        wo[s] = (const float*)d_in[base + 4];
        bo[s] = (const float*)d_in[base + 5];
    }

    char* ws = (char*)d_ws;
    size_t off = 0;
    short* A  = (short*)(ws + off); off += (size_t)M_ROWS * KP_A * 2;   // 35.7 MB
    short* H1 = (short*)(ws + off); off += (size_t)M_ROWS * NF * 2;     // 33.6 MB
    short *Wta[3], *Wtr[3];
    for (int s = 0; s < 3; ++s) {
        Wta[s] = (short*)(ws + off); off += (size_t)NF * KP_A * 2;
        Wtr[s] = (short*)(ws + off); off += (size_t)NF * NF * 2;
    }
    float* out = (float*)d_out;

    k_latent<<<(M_ROWS * 64) / 256, 256, 0, stream>>>(latent, A);
    for (int s = 0; s < 3; ++s) {
        int din_a = (s == 0) ? 524 : 513;
        dim3 ga((KP_A + 31) / 32, NF / 32);
        k_wt<<<ga, 256, 0, stream>>>(wa[s], Wta[s], din_a, KP_A);
        dim3 gr(NF / 32, NF / 32);
        k_wt<<<gr, 256, 0, stream>>>(wr[s], Wtr[s], NF, NF);
    }
    k_knncov<<<2048, 256, 0, stream>>>(pc, A);

    dim3 gg(M_ROWS / BM, NF / BN);
    for (int s = 0; s < 3; ++s) {
        if (s > 0) k_packout<<<M_ROWS / 256, 256, 0, stream>>>(out, A);
        k_setbo<<<M_ROWS / 256, 256, 0, stream>>>(out, bo[s], s > 0 ? 1 : 0);
        k_gemm<<<gg, 256, 0, stream>>>(A,  Wta[s], ba[s], nullptr, H1,
                                       nullptr, nullptr, KP_A);
        k_gemm<<<gg, 256, 0, stream>>>(H1, Wtr[s], br[s], H1, nullptr,
                                       wo[s], out, NF);
    }
}

// Round 6
// 320.146 us; speedup vs baseline: 1.7191x; 1.0972x over previous
//
#include <hip/hip_runtime.h>
#include <hip/hip_bf16.h>

typedef __attribute__((ext_vector_type(8))) short short8;
typedef __attribute__((ext_vector_type(4))) float f32x4;

__device__ __forceinline__ short bf16r(float f) {
    union { float f; unsigned u; } v; v.f = f;
    unsigned u = (v.u + 0x7fffu + ((v.u >> 16) & 1u)) >> 16;
    return (short)u;
}
__device__ __forceinline__ float bf2f(short s) {
    union { unsigned u; float f; } v; v.u = ((unsigned)(unsigned short)s) << 16;
    return v.f;
}

// LDS bank swizzle for [row][32-short] tiles: 16B-slot s -> s ^ fswz(row).
// Involution; applied inverse on the global staging source, forward on ds_read.
__device__ __forceinline__ int fswz(int r) { return (r ^ (r >> 2)) & 3; }

// async global->LDS, 16B per lane; LDS dest = wave-uniform base + lane*16.
__device__ __forceinline__ void gl16(const short* g, short* l) {
    __builtin_amdgcn_global_load_lds(
        (const __attribute__((address_space(1))) unsigned int*)g,
        (__attribute__((address_space(3))) unsigned int*)l, 16, 0, 0);
}

#define M_ROWS 32768
#define KP_A 544      // padded K/stride for stage-a A and Wta (524 real for s=0)
#define NF 512

// latent (32768 x 512 f32) -> A[:, 0:512] bf16, row stride 544
__global__ __launch_bounds__(256) void k_latent(const float* __restrict__ latent,
                                                short* __restrict__ A) {
    int idx = blockIdx.x * 256 + threadIdx.x;   // one thread per 8 elements
    int row = idx >> 6;
    int c = (idx & 63) << 3;
    const float* src = latent + (long)row * NF + c;
    float4 f0 = *(const float4*)src;
    float4 f1 = *(const float4*)(src + 4);
    short8 o;
    o[0] = bf16r(f0.x); o[1] = bf16r(f0.y); o[2] = bf16r(f0.z); o[3] = bf16r(f0.w);
    o[4] = bf16r(f1.x); o[5] = bf16r(f1.y); o[6] = bf16r(f1.z); o[7] = bf16r(f1.w);
    *(short8*)(A + (long)row * KP_A + c) = o;
}

// All 6 weight transposes in one launch. z in [0,6): z<3 -> Wta[z] (stride 544,
// din 524/512/512), z>=3 -> Wtr[z-3] (stride 512, din 512). Zero-pad k>=din.
__global__ __launch_bounds__(256) void k_wt6(const float* __restrict__ w0,
                                             const float* __restrict__ w1,
                                             const float* __restrict__ w2,
                                             const float* __restrict__ w3,
                                             const float* __restrict__ w4,
                                             const float* __restrict__ w5,
                                             short* __restrict__ wdst) {
    int z = blockIdx.z;
    const float* W = (z == 0) ? w0 : (z == 1) ? w1 : (z == 2) ? w2
                   : (z == 3) ? w3 : (z == 4) ? w4 : w5;
    int din = (z == 0) ? 524 : 512;
    int Kp  = (z < 3) ? KP_A : NF;
    short* Wt = wdst + ((z < 3) ? (size_t)z * NF * KP_A
                                : (size_t)3 * NF * KP_A + (size_t)(z - 3) * NF * NF);
    int kt = blockIdx.x * 32;
    if (kt >= Kp) return;
    int nt = blockIdx.y * 32;
    __shared__ float tile[32][33];
    int tx = threadIdx.x & 31, ty = threadIdx.x >> 5;   // 32 x 8
    #pragma unroll
    for (int r = 0; r < 32; r += 8) {
        int k = kt + ty + r;
        tile[ty + r][tx] = (k < din) ? W[(long)k * NF + nt + tx] : 0.0f;
    }
    __syncthreads();
    #pragma unroll
    for (int r = 0; r < 32; r += 8) {
        int n = nt + ty + r, k = kt + tx;
        Wt[(long)n * Kp + k] = bf16r(tile[tx][ty + r]);
    }
}

__device__ __forceinline__ bool beats(float va, int ia, float vb, int ib) {
    return va > vb || (va == vb && ia < ib);
}

// per-batch kNN (top-2) + cov features -> A[:, 512:544].
// Grid: 16 batches x 128 chunks; block = 4 waves, 4 queries/wave.
// Branchless per-lane top-2 update (v_cndmask, no divergent branches).
__global__ __launch_bounds__(256, 2) void k_knncov(const float* __restrict__ pc,
                                                   short* __restrict__ A) {
    __shared__ float sx[2048], sy[2048], sz[2048], sq[2048];
    __shared__ int ires[32];          // [wid*8 + i*2 + {0,1}]
    int b = blockIdx.x >> 7;
    int chunk = blockIdx.x & 127;     // 16 queries per block
    const float* p = pc + (long)b * 2048 * 3;
    for (int i = threadIdx.x; i < 2048; i += 256) {
        float x = p[3 * i], y = p[3 * i + 1], z = p[3 * i + 2];
        sx[i] = x; sy[i] = y; sz[i] = z;
        sq[i] = x * x + y * y + z * z;
    }
    __syncthreads();
    int wid = threadIdx.x >> 6, lane = threadIdx.x & 63;
    int nbase = chunk * 16 + wid * 4;

    float qx[4], qy[4], qz[4], qq[4];
    #pragma unroll
    for (int i = 0; i < 4; ++i) {
        qx[i] = sx[nbase + i]; qy[i] = sy[nbase + i];
        qz[i] = sz[nbase + i]; qq[i] = sq[nbase + i];
    }
    float b0[4], b1[4]; int j0[4], j1[4];
    #pragma unroll
    for (int i = 0; i < 4; ++i) { b0[i] = -INFINITY; b1[i] = -INFINITY; j0[i] = 0; j1[i] = 0; }

    for (int it = 0; it < 32; ++it) {
        int m = it * 64 + lane;
        float mx = sx[m], my = sy[m], mz = sz[m], mq = sq[m];
        #pragma unroll
        for (int i = 0; i < 4; ++i) {
            float inner = qx[i] * mx + qy[i] * my + qz[i] * mz;
            float negd = -((qq[i] - 2.0f * inner) + mq);
            bool c0 = negd > b0[i];
            bool c1 = negd > b1[i];
            float t1 = c0 ? b0[i] : (c1 ? negd : b1[i]);
            int   u1 = c0 ? j0[i] : (c1 ? m : j1[i]);
            b1[i] = t1; j1[i] = u1;
            b0[i] = c0 ? negd : b0[i];
            j0[i] = c0 ? m : j0[i];
        }
    }

    #pragma unroll
    for (int i = 0; i < 4; ++i) {
        float v0 = b0[i], v1 = b1[i]; int k0 = j0[i], k1 = j1[i];
        #pragma unroll
        for (int off = 1; off < 64; off <<= 1) {
            float w0 = __shfl_xor(v0, off, 64), w1 = __shfl_xor(v1, off, 64);
            int   l0 = __shfl_xor(k0, off, 64), l1 = __shfl_xor(k1, off, 64);
            float n0v, n1v; int n0i, n1i;
            if (beats(v0, k0, w0, l0)) {
                n0v = v0; n0i = k0;
                if (beats(w0, l0, v1, k1)) { n1v = w0; n1i = l0; } else { n1v = v1; n1i = k1; }
            } else {
                n0v = w0; n0i = l0;
                if (beats(v0, k0, w1, l1)) { n1v = v0; n1i = k0; } else { n1v = w1; n1i = l1; }
            }
            v0 = n0v; k0 = n0i; v1 = n1v; k1 = n1i;
        }
        if (lane == 0) {
            ires[wid * 8 + i * 2]     = k0;
            ires[wid * 8 + i * 2 + 1] = k1;
        }
    }
    __syncthreads();
    if (threadIdx.x < 16) {
        int t = threadIdx.x;
        int k0 = ires[(t >> 2) * 8 + (t & 3) * 2];
        int k1 = ires[(t >> 2) * 8 + (t & 3) * 2 + 1];
        int n = chunk * 16 + t;
        float xn = sx[n], yn = sy[n], zn = sz[n];
        float a0 = sx[k0], a1 = sy[k0], a2 = sz[k0];
        float c0 = sx[k1], c1 = sy[k1], c2 = sz[k1];
        long row = (long)b * 2048 + n;
        short vals[32];
        vals[0] = bf16r(xn); vals[1] = bf16r(yn); vals[2] = bf16r(zn);
        float ou[9] = {a0 * c0, a0 * c1, a0 * c2,
                       a1 * c0, a1 * c1, a1 * c2,
                       a2 * c0, a2 * c1, a2 * c2};
        #pragma unroll
        for (int q = 0; q < 9; ++q) vals[3 + q] = bf16r(ou[q]);
        #pragma unroll
        for (int q = 12; q < 32; ++q) vals[q] = 0;
        short* dst = A + row * KP_A + NF;
        #pragma unroll
        for (int q = 0; q < 4; ++q)
            *(short8*)(dst + q * 8) = *(short8*)(vals + q * 8);
    }
}

// out = bo (add=0) or out += bo (add=1)
__global__ __launch_bounds__(256) void k_setbo(float* __restrict__ out,
                                               const float* __restrict__ bo, int add) {
    int i = blockIdx.x * 256 + threadIdx.x;
    float v = bo[0];
    out[i] = add ? (out[i] + v) : v;
}

// GEMM: 128x128 tile, BK=32, double-buffered LDS, global_load_lds width-16,
// XOR-swizzled staging, setprio around MFMA, XCD-aware block swizzle.
// Epilogues:
//  wov==null, wex==null: C = relu(A@Bt^T + bias)
//  wov==null, wex!=null: C = relu(A@Bt^T + bias + outv[row]*wex[col])  (rank-1)
//  wov!=null:            out[row] += sum_col relu(acc+bias+Res)*wov[col]
#define BM 128
#define BN 128
#define BK 32

__global__ __launch_bounds__(256) void k_gemm(const short* __restrict__ A,
                                              const short* __restrict__ Bt,
                                              const float* __restrict__ bias,
                                              const short* __restrict__ Res,
                                              short* __restrict__ C,
                                              const float* __restrict__ wov,
                                              float* __restrict__ outp,
                                              const float* __restrict__ wex,
                                              const float* __restrict__ outv,
                                              int lda, int kend) {
    __shared__ __align__(16) short As[2][BM * BK];
    __shared__ __align__(16) short Bs[2][BN * BK];
    // XCD swizzle (nwg % 8 == 0, bijective): XCD k gets a contiguous wgid chunk.
    int nwg = gridDim.x;
    int orig = blockIdx.x;
    int wgid = (orig & 7) * (nwg >> 3) + (orig >> 3);
    int bm = wgid >> 2, bn = wgid & 3;    // 4 bn-tiles (N=512) per bm
    int t = threadIdx.x, lane = t & 63, wid = t >> 6;
    int wm = wid >> 1, wn = wid & 1;
    f32x4 acc[4][4] = {};
    const long arow0 = (long)bm * BM, brow0 = (long)bn * BN;
    int l15 = lane & 15;

    // staging: wave wid owns 1KB chunks {wid*2, wid*2+1} of As and Bs.
    int rc0 = (wid * 2) * 16 + (lane >> 2);
    int rc1 = (wid * 2 + 1) * 16 + (lane >> 2);
    int ks0 = ((lane & 3) ^ fswz(rc0)) * 8;
    int ks1 = ((lane & 3) ^ fswz(rc1)) * 8;
    long aoff0 = (arow0 + rc0) * (long)lda + ks0;
    long aoff1 = (arow0 + rc1) * (long)lda + ks1;
    long boff0 = (brow0 + rc0) * (long)lda + ks0;
    long boff1 = (brow0 + rc1) * (long)lda + ks1;
    int cb0 = (wid * 2) * 512;
    int cb1 = (wid * 2 + 1) * 512;

    // fragment read offsets (shorts): logical slot (lane>>4) ^ fswz(row)
    int ra[4], rb[4];
    #pragma unroll
    for (int i = 0; i < 4; ++i) {
        int rA = wm * 64 + i * 16 + l15;
        int rB = wn * 64 + i * 16 + l15;
        ra[i] = rA * 32 + (((lane >> 4) ^ fswz(rA)) * 8);
        rb[i] = rB * 32 + (((lane >> 4) ^ fswz(rB)) * 8);
    }

#define STAGE(bufi, kt) do { \
        gl16(A + aoff0 + (kt), &As[bufi][cb0]); \
        gl16(A + aoff1 + (kt), &As[bufi][cb1]); \
        gl16(Bt + boff0 + (kt), &Bs[bufi][cb0]); \
        gl16(Bt + boff1 + (kt), &Bs[bufi][cb1]); \
    } while (0)

    int nt = kend / BK;
    STAGE(0, 0);
    __syncthreads();
    for (int kt = 0; kt < nt; ++kt) {
        int cur = kt & 1;
        if (kt + 1 < nt) STAGE(cur ^ 1, (kt + 1) * BK);
        short8 fa[4], fb[4];
        #pragma unroll
        for (int i = 0; i < 4; ++i) {
            fa[i] = *(const short8*)&As[cur][ra[i]];
            fb[i] = *(const short8*)&Bs[cur][rb[i]];
        }
        __builtin_amdgcn_s_setprio(1);
        #pragma unroll
        for (int i = 0; i < 4; ++i)
            #pragma unroll
            for (int j = 0; j < 4; ++j)
                acc[i][j] = __builtin_amdgcn_mfma_f32_16x16x32_bf16(fa[i], fb[j], acc[i][j], 0, 0, 0);
        __builtin_amdgcn_s_setprio(0);
        __syncthreads();   // drains vmcnt for next buf + protects cur from overwrite
    }
#undef STAGE

    int rq4 = (lane >> 4) * 4;
    if (wov == nullptr) {
        #pragma unroll
        for (int i = 0; i < 4; ++i) {
            #pragma unroll
            for (int j = 0; j < 4; ++j) {
                int col = bn * BN + wn * 64 + j * 16 + l15;
                float bval = bias[col];
                float wexv = wex ? wex[col] : 0.0f;
                #pragma unroll
                for (int r = 0; r < 4; ++r) {
                    long row = arow0 + wm * 64 + i * 16 + rq4 + r;
                    float v = acc[i][j][r] + bval;
                    if (wex) v += outv[row] * wexv;
                    v = fmaxf(v, 0.0f);
                    C[row * NF + col] = bf16r(v);
                }
            }
        }
    } else {
        float wv[4], bv[4];
        #pragma unroll
        for (int j = 0; j < 4; ++j) {
            int col = bn * BN + wn * 64 + j * 16 + l15;
            wv[j] = wov[col];
            bv[j] = bias[col];
        }
        #pragma unroll
        for (int i = 0; i < 4; ++i) {
            #pragma unroll
            for (int r = 0; r < 4; ++r) {
                long row = arow0 + wm * 64 + i * 16 + rq4 + r;
                float s = 0.0f;
                #pragma unroll
                for (int j = 0; j < 4; ++j) {
                    int col = bn * BN + wn * 64 + j * 16 + l15;
                    float v = acc[i][j][r] + bv[j] + bf2f(Res[row * NF + col]);
                    v = fmaxf(v, 0.0f);
                    s += v * wv[j];
                }
                s += __shfl_xor(s, 1, 64);
                s += __shfl_xor(s, 2, 64);
                s += __shfl_xor(s, 4, 64);
                s += __shfl_xor(s, 8, 64);
                if (l15 == 0) atomicAdd(outp + row, s);
            }
        }
    }
}

extern "C" void kernel_launch(void* const* d_in, const int* in_sizes, int n_in,
                              void* d_out, int out_size, void* d_ws, size_t ws_size,
                              hipStream_t stream) {
    (void)in_sizes; (void)n_in; (void)out_size; (void)ws_size;
    const float* latent = (const float*)d_in[0];
    const float* pc     = (const float*)d_in[1];
    const float *wa[3], *ba[3], *wr[3], *br[3], *wo[3], *bo[3];
    for (int s = 0; s < 3; ++s) {
        int base = 2 + s * 6;
        wa[s] = (const float*)d_in[base + 0];
        ba[s] = (const float*)d_in[base + 1];
        wr[s] = (const float*)d_in[base + 2];
        br[s] = (const float*)d_in[base + 3];
        wo[s] = (const float*)d_in[base + 4];
        bo[s] = (const float*)d_in[base + 5];
    }

    char* ws = (char*)d_ws;
    size_t off = 0;
    short* A  = (short*)(ws + off); off += (size_t)M_ROWS * KP_A * 2;   // 35.7 MB
    short* H1 = (short*)(ws + off); off += (size_t)M_ROWS * NF * 2;     // 33.6 MB
    short* Wbase = (short*)(ws + off);
    short *Wta[3], *Wtr[3];
    for (int s = 0; s < 3; ++s) { Wta[s] = Wbase + (size_t)s * NF * KP_A; }
    for (int s = 0; s < 3; ++s) { Wtr[s] = Wbase + (size_t)3 * NF * KP_A + (size_t)s * NF * NF; }
    float* out = (float*)d_out;

    k_latent<<<(M_ROWS * 64) / 256, 256, 0, stream>>>(latent, A);
    dim3 gw((KP_A + 31) / 32, NF / 32, 6);
    k_wt6<<<gw, 256, 0, stream>>>(wa[0], wa[1], wa[2], wr[0], wr[1], wr[2], Wbase);
    k_knncov<<<2048, 256, 0, stream>>>(pc, A);

    int nwg = (M_ROWS / BM) * (NF / BN);   // 1024, %8==0
    for (int s = 0; s < 3; ++s) {
        k_setbo<<<M_ROWS / 256, 256, 0, stream>>>(out, bo[s], s > 0 ? 1 : 0);
        if (s == 0) {
            k_gemm<<<nwg, 256, 0, stream>>>(A, Wta[0], ba[0], nullptr, H1,
                                            nullptr, nullptr, nullptr, nullptr,
                                            KP_A, KP_A);
        } else {
            // K=512 + rank-1 (out[row] * wa_row512[col]) in epilogue
            k_gemm<<<nwg, 256, 0, stream>>>(A, Wta[s], ba[s], nullptr, H1,
                                            nullptr, nullptr,
                                            wa[s] + (size_t)NF * NF, out,
                                            KP_A, NF);
        }
        k_gemm<<<nwg, 256, 0, stream>>>(H1, Wtr[s], br[s], H1, nullptr,
                                        wo[s], out, nullptr, nullptr,
                                        NF, NF);
    }
}

// Round 7
// 289.058 us; speedup vs baseline: 1.9040x; 1.1076x over previous
//
#include <hip/hip_runtime.h>
#include <hip/hip_bf16.h>

typedef __attribute__((ext_vector_type(8))) short short8;
typedef __attribute__((ext_vector_type(4))) float f32x4;

__device__ __forceinline__ short bf16r(float f) {
    union { float f; unsigned u; } v; v.f = f;
    unsigned u = (v.u + 0x7fffu + ((v.u >> 16) & 1u)) >> 16;
    return (short)u;
}
__device__ __forceinline__ float bf2f(short s) {
    union { unsigned u; float f; } v; v.u = ((unsigned)(unsigned short)s) << 16;
    return v.f;
}

// LDS bank swizzle for [row][32-short] tiles: 16B-slot s -> s ^ fswz(row).
// Involution; applied inverse on the global staging source, forward on ds_read.
__device__ __forceinline__ int fswz(int r) { return (r ^ (r >> 2)) & 3; }

// async global->LDS, 16B per lane; LDS dest = wave-uniform base + lane*16.
__device__ __forceinline__ void gl16(const short* g, short* l) {
    __builtin_amdgcn_global_load_lds(
        (const __attribute__((address_space(1))) unsigned int*)g,
        (__attribute__((address_space(3))) unsigned int*)l, 16, 0, 0);
}

#define M_ROWS 32768
#define KP_A 544      // padded K/stride for stage-a A and Wta (524 real for s=0)
#define NF 512

// latent (32768 x 512 f32) -> A[:, 0:512] bf16, row stride 544
__global__ __launch_bounds__(256) void k_latent(const float* __restrict__ latent,
                                                short* __restrict__ A) {
    int idx = blockIdx.x * 256 + threadIdx.x;   // one thread per 8 elements
    int row = idx >> 6;
    int c = (idx & 63) << 3;
    const float* src = latent + (long)row * NF + c;
    float4 f0 = *(const float4*)src;
    float4 f1 = *(const float4*)(src + 4);
    short8 o;
    o[0] = bf16r(f0.x); o[1] = bf16r(f0.y); o[2] = bf16r(f0.z); o[3] = bf16r(f0.w);
    o[4] = bf16r(f1.x); o[5] = bf16r(f1.y); o[6] = bf16r(f1.z); o[7] = bf16r(f1.w);
    *(short8*)(A + (long)row * KP_A + c) = o;
}

// All 6 weight transposes in one launch. z in [0,6): z<3 -> Wta[z] (stride 544,
// din 524/512/512), z>=3 -> Wtr[z-3] (stride 512, din 512). Zero-pad k>=din.
__global__ __launch_bounds__(256) void k_wt6(const float* __restrict__ w0,
                                             const float* __restrict__ w1,
                                             const float* __restrict__ w2,
                                             const float* __restrict__ w3,
                                             const float* __restrict__ w4,
                                             const float* __restrict__ w5,
                                             short* __restrict__ wdst) {
    int z = blockIdx.z;
    const float* W = (z == 0) ? w0 : (z == 1) ? w1 : (z == 2) ? w2
                   : (z == 3) ? w3 : (z == 4) ? w4 : w5;
    int din = (z == 0) ? 524 : 512;
    int Kp  = (z < 3) ? KP_A : NF;
    short* Wt = wdst + ((z < 3) ? (size_t)z * NF * KP_A
                                : (size_t)3 * NF * KP_A + (size_t)(z - 3) * NF * NF);
    int kt = blockIdx.x * 32;
    if (kt >= Kp) return;
    int nt = blockIdx.y * 32;
    __shared__ float tile[32][33];
    int tx = threadIdx.x & 31, ty = threadIdx.x >> 5;   // 32 x 8
    #pragma unroll
    for (int r = 0; r < 32; r += 8) {
        int k = kt + ty + r;
        tile[ty + r][tx] = (k < din) ? W[(long)k * NF + nt + tx] : 0.0f;
    }
    __syncthreads();
    #pragma unroll
    for (int r = 0; r < 32; r += 8) {
        int n = nt + ty + r, k = kt + tx;
        Wt[(long)n * Kp + k] = bf16r(tile[tx][ty + r]);
    }
}

__device__ __forceinline__ bool beats(float va, int ia, float vb, int ib) {
    return va > vb || (va == vb && ia < ib);
}

// per-batch kNN (top-2) + cov features -> A[:, 512:544].
// Grid: 16 batches x 128 chunks; block = 4 waves, 4 queries/wave.
// Branchless per-lane top-2 update (v_cndmask, no divergent branches).
__global__ __launch_bounds__(256, 2) void k_knncov(const float* __restrict__ pc,
                                                   short* __restrict__ A) {
    __shared__ float sx[2048], sy[2048], sz[2048], sq[2048];
    __shared__ int ires[32];          // [wid*8 + i*2 + {0,1}]
    int b = blockIdx.x >> 7;
    int chunk = blockIdx.x & 127;     // 16 queries per block
    const float* p = pc + (long)b * 2048 * 3;
    for (int i = threadIdx.x; i < 2048; i += 256) {
        float x = p[3 * i], y = p[3 * i + 1], z = p[3 * i + 2];
        sx[i] = x; sy[i] = y; sz[i] = z;
        sq[i] = x * x + y * y + z * z;
    }
    __syncthreads();
    int wid = threadIdx.x >> 6, lane = threadIdx.x & 63;
    int nbase = chunk * 16 + wid * 4;

    float qx[4], qy[4], qz[4], qq[4];
    #pragma unroll
    for (int i = 0; i < 4; ++i) {
        qx[i] = sx[nbase + i]; qy[i] = sy[nbase + i];
        qz[i] = sz[nbase + i]; qq[i] = sq[nbase + i];
    }
    float b0[4], b1[4]; int j0[4], j1[4];
    #pragma unroll
    for (int i = 0; i < 4; ++i) { b0[i] = -INFINITY; b1[i] = -INFINITY; j0[i] = 0; j1[i] = 0; }

    for (int it = 0; it < 32; ++it) {
        int m = it * 64 + lane;
        float mx = sx[m], my = sy[m], mz = sz[m], mq = sq[m];
        #pragma unroll
        for (int i = 0; i < 4; ++i) {
            float inner = qx[i] * mx + qy[i] * my + qz[i] * mz;
            float negd = -((qq[i] - 2.0f * inner) + mq);
            bool c0 = negd > b0[i];
            bool c1 = negd > b1[i];
            float t1 = c0 ? b0[i] : (c1 ? negd : b1[i]);
            int   u1 = c0 ? j0[i] : (c1 ? m : j1[i]);
            b1[i] = t1; j1[i] = u1;
            b0[i] = c0 ? negd : b0[i];
            j0[i] = c0 ? m : j0[i];
        }
    }

    #pragma unroll
    for (int i = 0; i < 4; ++i) {
        float v0 = b0[i], v1 = b1[i]; int k0 = j0[i], k1 = j1[i];
        #pragma unroll
        for (int off = 1; off < 64; off <<= 1) {
            float w0 = __shfl_xor(v0, off, 64), w1 = __shfl_xor(v1, off, 64);
            int   l0 = __shfl_xor(k0, off, 64), l1 = __shfl_xor(k1, off, 64);
            float n0v, n1v; int n0i, n1i;
            if (beats(v0, k0, w0, l0)) {
                n0v = v0; n0i = k0;
                if (beats(w0, l0, v1, k1)) { n1v = w0; n1i = l0; } else { n1v = v1; n1i = k1; }
            } else {
                n0v = w0; n0i = l0;
                if (beats(v0, k0, w1, l1)) { n1v = v0; n1i = k0; } else { n1v = w1; n1i = l1; }
            }
            v0 = n0v; k0 = n0i; v1 = n1v; k1 = n1i;
        }
        if (lane == 0) {
            ires[wid * 8 + i * 2]     = k0;
            ires[wid * 8 + i * 2 + 1] = k1;
        }
    }
    __syncthreads();
    if (threadIdx.x < 16) {
        int t = threadIdx.x;
        int k0 = ires[(t >> 2) * 8 + (t & 3) * 2];
        int k1 = ires[(t >> 2) * 8 + (t & 3) * 2 + 1];
        int n = chunk * 16 + t;
        float xn = sx[n], yn = sy[n], zn = sz[n];
        float a0 = sx[k0], a1 = sy[k0], a2 = sz[k0];
        float c0 = sx[k1], c1 = sy[k1], c2 = sz[k1];
        long row = (long)b * 2048 + n;
        short vals[32];
        vals[0] = bf16r(xn); vals[1] = bf16r(yn); vals[2] = bf16r(zn);
        float ou[9] = {a0 * c0, a0 * c1, a0 * c2,
                       a1 * c0, a1 * c1, a1 * c2,
                       a2 * c0, a2 * c1, a2 * c2};
        #pragma unroll
        for (int q = 0; q < 9; ++q) vals[3 + q] = bf16r(ou[q]);
        #pragma unroll
        for (int q = 12; q < 32; ++q) vals[q] = 0;
        short* dst = A + row * KP_A + NF;
        #pragma unroll
        for (int q = 0; q < 4; ++q)
            *(short8*)(dst + q * 8) = *(short8*)(vals + q * 8);
    }
}

// out = bo (add=0) or out += bo (add=1)
__global__ __launch_bounds__(256) void k_setbo(float* __restrict__ out,
                                               const float* __restrict__ bo, int add) {
    int i = blockIdx.x * 256 + threadIdx.x;
    float v = bo[0];
    out[i] = add ? (out[i] + v) : v;
}

// GEMM: 128x128 tile, BK=32, 3-buffer LDS pipeline with counted vmcnt
// (loads stay in flight across the raw s_barrier — never vmcnt(0) mid-loop),
// global_load_lds width-16, XOR-swizzled staging, setprio around MFMA,
// XCD-aware block swizzle.
// Epilogues:
//  wov==null, wex==null: C = relu(A@Bt^T + bias)
//  wov==null, wex!=null: C = relu(A@Bt^T + bias + outv[row]*wex[col])  (rank-1)
//  wov!=null:            out[row] += sum_col relu(acc+bias+Res)*wov[col] (+bo once)
#define BM 128
#define BN 128
#define BK 32

__global__ __launch_bounds__(256) void k_gemm(const short* __restrict__ A,
                                              const short* __restrict__ Bt,
                                              const float* __restrict__ bias,
                                              const short* __restrict__ Res,
                                              short* __restrict__ C,
                                              const float* __restrict__ wov,
                                              float* __restrict__ outp,
                                              const float* __restrict__ wex,
                                              const float* __restrict__ outv,
                                              const float* __restrict__ bov,
                                              int lda, int kend) {
    __shared__ __align__(16) short As[3][BM * BK];
    __shared__ __align__(16) short Bs[3][BN * BK];
    // XCD swizzle (nwg % 8 == 0, bijective): XCD k gets a contiguous wgid chunk.
    int nwg = gridDim.x;
    int orig = blockIdx.x;
    int wgid = (orig & 7) * (nwg >> 3) + (orig >> 3);
    int bm = wgid >> 2, bn = wgid & 3;    // 4 bn-tiles (N=512) per bm
    int t = threadIdx.x, lane = t & 63, wid = t >> 6;
    int wm = wid >> 1, wn = wid & 1;
    f32x4 acc[4][4] = {};
    const long arow0 = (long)bm * BM, brow0 = (long)bn * BN;
    int l15 = lane & 15;

    // staging: wave wid owns 1KB chunks {wid*2, wid*2+1} of As and Bs.
    int rc0 = (wid * 2) * 16 + (lane >> 2);
    int rc1 = (wid * 2 + 1) * 16 + (lane >> 2);
    int ks0 = ((lane & 3) ^ fswz(rc0)) * 8;
    int ks1 = ((lane & 3) ^ fswz(rc1)) * 8;
    long aoff0 = (arow0 + rc0) * (long)lda + ks0;
    long aoff1 = (arow0 + rc1) * (long)lda + ks1;
    long boff0 = (brow0 + rc0) * (long)lda + ks0;
    long boff1 = (brow0 + rc1) * (long)lda + ks1;
    int cb0 = (wid * 2) * 512;
    int cb1 = (wid * 2 + 1) * 512;

    // fragment read offsets (shorts): logical slot (lane>>4) ^ fswz(row)
    int ra[4], rb[4];
    #pragma unroll
    for (int i = 0; i < 4; ++i) {
        int rA = wm * 64 + i * 16 + l15;
        int rB = wn * 64 + i * 16 + l15;
        ra[i] = rA * 32 + (((lane >> 4) ^ fswz(rA)) * 8);
        rb[i] = rB * 32 + (((lane >> 4) ^ fswz(rB)) * 8);
    }

#define STAGE(bufi, ktoff) do { \
        gl16(A  + aoff0 + (ktoff), &As[bufi][cb0]); \
        gl16(A  + aoff1 + (ktoff), &As[bufi][cb1]); \
        gl16(Bt + boff0 + (ktoff), &Bs[bufi][cb0]); \
        gl16(Bt + boff1 + (ktoff), &Bs[bufi][cb1]); \
    } while (0)

    int nt = kend / BK;
    // prologue: tiles 0,1 in flight; wait tile 0 only.
    STAGE(0, 0);
    STAGE(1, BK);
    asm volatile("s_waitcnt vmcnt(4)" ::: "memory");
    __builtin_amdgcn_sched_barrier(0);
    __builtin_amdgcn_s_barrier();

    int cur = 0;
    for (int kt = 0; kt < nt; ++kt) {
        short8 fa[4], fb[4];
        #pragma unroll
        for (int i = 0; i < 4; ++i) {
            fa[i] = *(const short8*)&As[cur][ra[i]];
            fb[i] = *(const short8*)&Bs[cur][rb[i]];
        }
        if (kt + 2 < nt) {
            // overwrite buffer (kt+2)%3 == (kt-1)%3: its readers finished
            // before iteration kt-1's barrier, which all waves have passed.
            int stg = (cur >= 1) ? cur - 1 : 2;
            STAGE(stg, (kt + 2) * BK);
            // wait: my tile-(kt+1) loads landed (oldest 4 of 8) + my ds_reads
            // done (so others may overwrite As[cur] next iteration).
            asm volatile("s_waitcnt vmcnt(4) lgkmcnt(0)" ::: "memory");
            __builtin_amdgcn_sched_barrier(0);
            __builtin_amdgcn_s_barrier();
        } else if (kt + 1 < nt) {
            asm volatile("s_waitcnt vmcnt(0) lgkmcnt(0)" ::: "memory");
            __builtin_amdgcn_sched_barrier(0);
            __builtin_amdgcn_s_barrier();
        }
        __builtin_amdgcn_s_setprio(1);
        #pragma unroll
        for (int i = 0; i < 4; ++i)
            #pragma unroll
            for (int j = 0; j < 4; ++j)
                acc[i][j] = __builtin_amdgcn_mfma_f32_16x16x32_bf16(fa[i], fb[j], acc[i][j], 0, 0, 0);
        __builtin_amdgcn_s_setprio(0);
        cur = (cur >= 2) ? 0 : cur + 1;
    }
#undef STAGE

    int rq4 = (lane >> 4) * 4;
    if (wov == nullptr) {
        #pragma unroll
        for (int i = 0; i < 4; ++i) {
            #pragma unroll
            for (int j = 0; j < 4; ++j) {
                int col = bn * BN + wn * 64 + j * 16 + l15;
                float bval = bias[col];
                float wexv = wex ? wex[col] : 0.0f;
                #pragma unroll
                for (int r = 0; r < 4; ++r) {
                    long row = arow0 + wm * 64 + i * 16 + rq4 + r;
                    float v = acc[i][j][r] + bval;
                    if (wex) v += outv[row] * wexv;
                    v = fmaxf(v, 0.0f);
                    C[row * NF + col] = bf16r(v);
                }
            }
        }
    } else {
        float wv[4], bv[4];
        #pragma unroll
        for (int j = 0; j < 4; ++j) {
            int col = bn * BN + wn * 64 + j * 16 + l15;
            wv[j] = wov[col];
            bv[j] = bias[col];
        }
        float boadd = (bov != nullptr && wn == 0 && bn == 0) ? bov[0] : 0.0f;
        #pragma unroll
        for (int i = 0; i < 4; ++i) {
            #pragma unroll
            for (int r = 0; r < 4; ++r) {
                long row = arow0 + wm * 64 + i * 16 + rq4 + r;
                float s = 0.0f;
                #pragma unroll
                for (int j = 0; j < 4; ++j) {
                    int col = bn * BN + wn * 64 + j * 16 + l15;
                    float v = acc[i][j][r] + bv[j] + bf2f(Res[row * NF + col]);
                    v = fmaxf(v, 0.0f);
                    s += v * wv[j];
                }
                s += __shfl_xor(s, 1, 64);
                s += __shfl_xor(s, 2, 64);
                s += __shfl_xor(s, 4, 64);
                s += __shfl_xor(s, 8, 64);
                if (l15 == 0) atomicAdd(outp + row, s + boadd);
            }
        }
    }
}

extern "C" void kernel_launch(void* const* d_in, const int* in_sizes, int n_in,
                              void* d_out, int out_size, void* d_ws, size_t ws_size,
                              hipStream_t stream) {
    (void)in_sizes; (void)n_in; (void)out_size; (void)ws_size;
    const float* latent = (const float*)d_in[0];
    const float* pc     = (const float*)d_in[1];
    const float *wa[3], *ba[3], *wr[3], *br[3], *wo[3], *bo[3];
    for (int s = 0; s < 3; ++s) {
        int base = 2 + s * 6;
        wa[s] = (const float*)d_in[base + 0];
        ba[s] = (const float*)d_in[base + 1];
        wr[s] = (const float*)d_in[base + 2];
        br[s] = (const float*)d_in[base + 3];
        wo[s] = (const float*)d_in[base + 4];
        bo[s] = (const float*)d_in[base + 5];
    }

    char* ws = (char*)d_ws;
    size_t off = 0;
    short* A  = (short*)(ws + off); off += (size_t)M_ROWS * KP_A * 2;   // 35.7 MB
    short* H1 = (short*)(ws + off); off += (size_t)M_ROWS * NF * 2;     // 33.6 MB
    short* Wbase = (short*)(ws + off);
    short *Wta[3], *Wtr[3];
    for (int s = 0; s < 3; ++s) { Wta[s] = Wbase + (size_t)s * NF * KP_A; }
    for (int s = 0; s < 3; ++s) { Wtr[s] = Wbase + (size_t)3 * NF * KP_A + (size_t)s * NF * NF; }
    float* out = (float*)d_out;

    k_latent<<<(M_ROWS * 64) / 256, 256, 0, stream>>>(latent, A);
    dim3 gw((KP_A + 31) / 32, NF / 32, 6);
    k_wt6<<<gw, 256, 0, stream>>>(wa[0], wa[1], wa[2], wr[0], wr[1], wr[2], Wbase);
    k_knncov<<<2048, 256, 0, stream>>>(pc, A);
    k_setbo<<<M_ROWS / 256, 256, 0, stream>>>(out, bo[0], 0);

    int nwg = (M_ROWS / BM) * (NF / BN);   // 1024, %8==0
    for (int s = 0; s < 3; ++s) {
        if (s == 0) {
            k_gemm<<<nwg, 256, 0, stream>>>(A, Wta[0], ba[0], nullptr, H1,
                                            nullptr, nullptr, nullptr, nullptr,
                                            nullptr, KP_A, KP_A);
        } else {
            // K=512 + rank-1 (out[row] * wa_row512[col]) in epilogue
            k_gemm<<<nwg, 256, 0, stream>>>(A, Wta[s], ba[s], nullptr, H1,
                                            nullptr, nullptr,
                                            wa[s] + (size_t)NF * NF, out,
                                            nullptr, KP_A, NF);
        }
        k_gemm<<<nwg, 256, 0, stream>>>(H1, Wtr[s], br[s], H1, nullptr,
                                        wo[s], out, nullptr, nullptr,
                                        s > 0 ? bo[s] : nullptr, NF, NF);
    }
}

// Round 8
// 224.530 us; speedup vs baseline: 2.4512x; 1.2874x over previous
//
#include <hip/hip_runtime.h>
#include <hip/hip_bf16.h>

typedef __attribute__((ext_vector_type(8))) short short8;
typedef __attribute__((ext_vector_type(4))) float f32x4;

__device__ __forceinline__ short bf16r(float f) {
    union { float f; unsigned u; } v; v.f = f;
    unsigned u = (v.u + 0x7fffu + ((v.u >> 16) & 1u)) >> 16;
    return (short)u;
}
__device__ __forceinline__ float bf2f(short s) {
    union { unsigned u; float f; } v; v.u = ((unsigned)(unsigned short)s) << 16;
    return v.f;
}

// LDS bank swizzle for [row][32-short] tiles: 16B-slot s -> s ^ fswz(row).
// Involution; applied inverse on the global staging source, forward on ds_read.
__device__ __forceinline__ int fswz(int r) { return (r ^ (r >> 2)) & 3; }

// async global->LDS, 16B per lane; LDS dest = wave-uniform base + lane*16.
__device__ __forceinline__ void gl16(const short* g, short* l) {
    __builtin_amdgcn_global_load_lds(
        (const __attribute__((address_space(1))) unsigned int*)g,
        (__attribute__((address_space(3))) unsigned int*)l, 16, 0, 0);
}

#define M_ROWS 32768
#define KP_A 544      // padded K/stride for stage-a A and Wta (524 real for s=0)
#define NF 512

// latent (32768 x 512 f32) -> A[:, 0:512] bf16, row stride 544
__global__ __launch_bounds__(256) void k_latent(const float* __restrict__ latent,
                                                short* __restrict__ A) {
    int idx = blockIdx.x * 256 + threadIdx.x;   // one thread per 8 elements
    int row = idx >> 6;
    int c = (idx & 63) << 3;
    const float* src = latent + (long)row * NF + c;
    float4 f0 = *(const float4*)src;
    float4 f1 = *(const float4*)(src + 4);
    short8 o;
    o[0] = bf16r(f0.x); o[1] = bf16r(f0.y); o[2] = bf16r(f0.z); o[3] = bf16r(f0.w);
    o[4] = bf16r(f1.x); o[5] = bf16r(f1.y); o[6] = bf16r(f1.z); o[7] = bf16r(f1.w);
    *(short8*)(A + (long)row * KP_A + c) = o;
}

// All 6 weight transposes in one launch. z in [0,6): z<3 -> Wta[z] (stride 544,
// din 524/512/512), z>=3 -> Wtr[z-3] (stride 512, din 512). Zero-pad k>=din.
__global__ __launch_bounds__(256) void k_wt6(const float* __restrict__ w0,
                                             const float* __restrict__ w1,
                                             const float* __restrict__ w2,
                                             const float* __restrict__ w3,
                                             const float* __restrict__ w4,
                                             const float* __restrict__ w5,
                                             short* __restrict__ wdst) {
    int z = blockIdx.z;
    const float* W = (z == 0) ? w0 : (z == 1) ? w1 : (z == 2) ? w2
                   : (z == 3) ? w3 : (z == 4) ? w4 : w5;
    int din = (z == 0) ? 524 : 512;
    int Kp  = (z < 3) ? KP_A : NF;
    short* Wt = wdst + ((z < 3) ? (size_t)z * NF * KP_A
                                : (size_t)3 * NF * KP_A + (size_t)(z - 3) * NF * NF);
    int kt = blockIdx.x * 32;
    if (kt >= Kp) return;
    int nt = blockIdx.y * 32;
    __shared__ float tile[32][33];
    int tx = threadIdx.x & 31, ty = threadIdx.x >> 5;   // 32 x 8
    #pragma unroll
    for (int r = 0; r < 32; r += 8) {
        int k = kt + ty + r;
        tile[ty + r][tx] = (k < din) ? W[(long)k * NF + nt + tx] : 0.0f;
    }
    __syncthreads();
    #pragma unroll
    for (int r = 0; r < 32; r += 8) {
        int n = nt + ty + r, k = kt + tx;
        Wt[(long)n * Kp + k] = bf16r(tile[tx][ty + r]);
    }
}

__device__ __forceinline__ bool beats(float va, int ia, float vb, int ib) {
    return va > vb || (va == vb && ia < ib);
}

// per-batch kNN (top-2) + cov features -> A[:, 512:544].
// Grid: 16 batches x 128 chunks; block = 4 waves, 4 queries/wave.
// Branchless per-lane top-2 update (v_cndmask, no divergent branches).
__global__ __launch_bounds__(256, 2) void k_knncov(const float* __restrict__ pc,
                                                   short* __restrict__ A) {
    __shared__ float sx[2048], sy[2048], sz[2048], sq[2048];
    __shared__ int ires[32];          // [wid*8 + i*2 + {0,1}]
    int b = blockIdx.x >> 7;
    int chunk = blockIdx.x & 127;     // 16 queries per block
    const float* p = pc + (long)b * 2048 * 3;
    for (int i = threadIdx.x; i < 2048; i += 256) {
        float x = p[3 * i], y = p[3 * i + 1], z = p[3 * i + 2];
        sx[i] = x; sy[i] = y; sz[i] = z;
        sq[i] = x * x + y * y + z * z;
    }
    __syncthreads();
    int wid = threadIdx.x >> 6, lane = threadIdx.x & 63;
    int nbase = chunk * 16 + wid * 4;

    float qx[4], qy[4], qz[4], qq[4];
    #pragma unroll
    for (int i = 0; i < 4; ++i) {
        qx[i] = sx[nbase + i]; qy[i] = sy[nbase + i];
        qz[i] = sz[nbase + i]; qq[i] = sq[nbase + i];
    }
    float b0[4], b1[4]; int j0[4], j1[4];
    #pragma unroll
    for (int i = 0; i < 4; ++i) { b0[i] = -INFINITY; b1[i] = -INFINITY; j0[i] = 0; j1[i] = 0; }

    for (int it = 0; it < 32; ++it) {
        int m = it * 64 + lane;
        float mx = sx[m], my = sy[m], mz = sz[m], mq = sq[m];
        #pragma unroll
        for (int i = 0; i < 4; ++i) {
            float inner = qx[i] * mx + qy[i] * my + qz[i] * mz;
            float negd = -((qq[i] - 2.0f * inner) + mq);
            bool c0 = negd > b0[i];
            bool c1 = negd > b1[i];
            float t1 = c0 ? b0[i] : (c1 ? negd : b1[i]);
            int   u1 = c0 ? j0[i] : (c1 ? m : j1[i]);
            b1[i] = t1; j1[i] = u1;
            b0[i] = c0 ? negd : b0[i];
            j0[i] = c0 ? m : j0[i];
        }
    }

    #pragma unroll
    for (int i = 0; i < 4; ++i) {
        float v0 = b0[i], v1 = b1[i]; int k0 = j0[i], k1 = j1[i];
        #pragma unroll
        for (int off = 1; off < 64; off <<= 1) {
            float w0 = __shfl_xor(v0, off, 64), w1 = __shfl_xor(v1, off, 64);
            int   l0 = __shfl_xor(k0, off, 64), l1 = __shfl_xor(k1, off, 64);
            float n0v, n1v; int n0i, n1i;
            if (beats(v0, k0, w0, l0)) {
                n0v = v0; n0i = k0;
                if (beats(w0, l0, v1, k1)) { n1v = w0; n1i = l0; } else { n1v = v1; n1i = k1; }
            } else {
                n0v = w0; n0i = l0;
                if (beats(v0, k0, w1, l1)) { n1v = v0; n1i = k0; } else { n1v = w1; n1i = l1; }
            }
            v0 = n0v; k0 = n0i; v1 = n1v; k1 = n1i;
        }
        if (lane == 0) {
            ires[wid * 8 + i * 2]     = k0;
            ires[wid * 8 + i * 2 + 1] = k1;
        }
    }
    __syncthreads();
    if (threadIdx.x < 16) {
        int t = threadIdx.x;
        int k0 = ires[(t >> 2) * 8 + (t & 3) * 2];
        int k1 = ires[(t >> 2) * 8 + (t & 3) * 2 + 1];
        int n = chunk * 16 + t;
        float xn = sx[n], yn = sy[n], zn = sz[n];
        float a0 = sx[k0], a1 = sy[k0], a2 = sz[k0];
        float c0 = sx[k1], c1 = sy[k1], c2 = sz[k1];
        long row = (long)b * 2048 + n;
        short vals[32];
        vals[0] = bf16r(xn); vals[1] = bf16r(yn); vals[2] = bf16r(zn);
        float ou[9] = {a0 * c0, a0 * c1, a0 * c2,
                       a1 * c0, a1 * c1, a1 * c2,
                       a2 * c0, a2 * c1, a2 * c2};
        #pragma unroll
        for (int q = 0; q < 9; ++q) vals[3 + q] = bf16r(ou[q]);
        #pragma unroll
        for (int q = 12; q < 32; ++q) vals[q] = 0;
        short* dst = A + row * KP_A + NF;
        #pragma unroll
        for (int q = 0; q < 4; ++q)
            *(short8*)(dst + q * 8) = *(short8*)(vals + q * 8);
    }
}

// out = bo (add=0) or out += bo (add=1)
__global__ __launch_bounds__(256) void k_setbo(float* __restrict__ out,
                                               const float* __restrict__ bo, int add) {
    int i = blockIdx.x * 256 + threadIdx.x;
    float v = bo[0];
    out[i] = add ? (out[i] + v) : v;
}

// GEMM: 256x128 tile, 8 waves (512 thr), BK=32, 3-buffer LDS pipeline with
// counted vmcnt (never 0 mid-loop), global_load_lds width-16, XOR-swizzled
// staging, setprio around MFMA, bijective XCD block swizzle.
// Epilogues:
//  wov==null, wex==null: C = relu(A@Bt^T + bias)
//  wov==null, wex!=null: C = relu(A@Bt^T + bias + outv[row]*wex[col])  (rank-1)
//  wov!=null:            out[row] += sum_col relu(acc+bias+Res)*wov[col] (+bo once)
#define BM 256
#define BN 128
#define BK 32

__global__ __launch_bounds__(512, 4) void k_gemm(const short* __restrict__ A,
                                                 const short* __restrict__ Bt,
                                                 const float* __restrict__ bias,
                                                 const short* __restrict__ Res,
                                                 short* __restrict__ C,
                                                 const float* __restrict__ wov,
                                                 float* __restrict__ outp,
                                                 const float* __restrict__ wex,
                                                 const float* __restrict__ outv,
                                                 const float* __restrict__ bov,
                                                 int lda, int kend) {
    __shared__ __align__(16) short As[3][BM * BK];   // 3 x 16KB
    __shared__ __align__(16) short Bs[3][BN * BK];   // 3 x 8KB
    // XCD swizzle (nwg % 8 == 0, bijective): XCD k gets a contiguous wgid chunk.
    int nwg = gridDim.x;
    int orig = blockIdx.x;
    int wgid = (orig & 7) * (nwg >> 3) + (orig >> 3);
    int bm = wgid >> 2, bn = wgid & 3;    // 4 bn-tiles (N=512) per bm
    int t = threadIdx.x, lane = t & 63, wid = t >> 6;   // wid 0..7
    int wm = wid >> 1, wn = wid & 1;
    f32x4 acc[4][4] = {};
    const long arow0 = (long)bm * BM, brow0 = (long)bn * BN;
    int l15 = lane & 15;

    // staging: wave wid owns A chunks {2w,2w+1} (rows 32w..32w+31) and
    // B chunk w (rows 16w..16w+15). 1KB chunk: lane l -> row +l>>2, slot l&3.
    int rcA0 = (wid * 2) * 16 + (lane >> 2);
    int rcA1 = (wid * 2 + 1) * 16 + (lane >> 2);
    int rcB  = wid * 16 + (lane >> 2);
    int ksA0 = ((lane & 3) ^ fswz(rcA0)) * 8;
    int ksA1 = ((lane & 3) ^ fswz(rcA1)) * 8;
    int ksB  = ((lane & 3) ^ fswz(rcB)) * 8;
    long aoff0 = (arow0 + rcA0) * (long)lda + ksA0;
    long aoff1 = (arow0 + rcA1) * (long)lda + ksA1;
    long boff  = (brow0 + rcB) * (long)lda + ksB;
    int cbA0 = (wid * 2) * 512;
    int cbA1 = (wid * 2 + 1) * 512;
    int cbB  = wid * 512;

    // fragment read offsets (shorts): logical slot (lane>>4) ^ fswz(row)
    int ra[4], rb[4];
    #pragma unroll
    for (int i = 0; i < 4; ++i) {
        int rA = wm * 64 + i * 16 + l15;
        int rB = wn * 64 + i * 16 + l15;
        ra[i] = rA * 32 + (((lane >> 4) ^ fswz(rA)) * 8);
        rb[i] = rB * 32 + (((lane >> 4) ^ fswz(rB)) * 8);
    }

#define STAGE(bufi, ktoff) do { \
        gl16(A  + aoff0 + (ktoff), &As[bufi][cbA0]); \
        gl16(A  + aoff1 + (ktoff), &As[bufi][cbA1]); \
        gl16(Bt + boff  + (ktoff), &Bs[bufi][cbB]); \
    } while (0)

    int nt = kend / BK;
    // prologue: tiles 0,1 in flight (3 loads each); wait tile 0 only.
    STAGE(0, 0);
    STAGE(1, BK);
    asm volatile("s_waitcnt vmcnt(3)" ::: "memory");
    __builtin_amdgcn_sched_barrier(0);
    __builtin_amdgcn_s_barrier();

    int cur = 0;
    for (int kt = 0; kt < nt; ++kt) {
        short8 fa[4], fb[4];
        #pragma unroll
        for (int i = 0; i < 4; ++i) {
            fa[i] = *(const short8*)&As[cur][ra[i]];
            fb[i] = *(const short8*)&Bs[cur][rb[i]];
        }
        if (kt + 2 < nt) {
            // overwrite buffer (kt+2)%3 == (kt-1)%3: its readers finished
            // before iteration kt-1's barrier, which all waves have passed.
            int stg = (cur >= 1) ? cur - 1 : 2;
            STAGE(stg, (kt + 2) * BK);
            // wait: tile-(kt+1) loads landed (oldest 3 of 6) + my ds_reads
            // done (so others may overwrite As[cur] next iteration).
            asm volatile("s_waitcnt vmcnt(3) lgkmcnt(0)" ::: "memory");
            __builtin_amdgcn_sched_barrier(0);
            __builtin_amdgcn_s_barrier();
        } else if (kt + 1 < nt) {
            asm volatile("s_waitcnt vmcnt(0) lgkmcnt(0)" ::: "memory");
            __builtin_amdgcn_sched_barrier(0);
            __builtin_amdgcn_s_barrier();
        }
        __builtin_amdgcn_s_setprio(1);
        #pragma unroll
        for (int i = 0; i < 4; ++i)
            #pragma unroll
            for (int j = 0; j < 4; ++j)
                acc[i][j] = __builtin_amdgcn_mfma_f32_16x16x32_bf16(fa[i], fb[j], acc[i][j], 0, 0, 0);
        __builtin_amdgcn_s_setprio(0);
        cur = (cur >= 2) ? 0 : cur + 1;
    }
#undef STAGE

    int rq4 = (lane >> 4) * 4;
    if (wov == nullptr) {
        #pragma unroll
        for (int i = 0; i < 4; ++i) {
            #pragma unroll
            for (int j = 0; j < 4; ++j) {
                int col = bn * BN + wn * 64 + j * 16 + l15;
                float bval = bias[col];
                float wexv = wex ? wex[col] : 0.0f;
                #pragma unroll
                for (int r = 0; r < 4; ++r) {
                    long row = arow0 + wm * 64 + i * 16 + rq4 + r;
                    float v = acc[i][j][r] + bval;
                    if (wex) v += outv[row] * wexv;
                    v = fmaxf(v, 0.0f);
                    C[row * NF + col] = bf16r(v);
                }
            }
        }
    } else {
        float wv[4], bv[4];
        #pragma unroll
        for (int j = 0; j < 4; ++j) {
            int col = bn * BN + wn * 64 + j * 16 + l15;
            wv[j] = wov[col];
            bv[j] = bias[col];
        }
        float boadd = (bov != nullptr && wn == 0 && bn == 0) ? bov[0] : 0.0f;
        #pragma unroll
        for (int i = 0; i < 4; ++i) {
            #pragma unroll
            for (int r = 0; r < 4; ++r) {
                long row = arow0 + wm * 64 + i * 16 + rq4 + r;
                float s = 0.0f;
                #pragma unroll
                for (int j = 0; j < 4; ++j) {
                    int col = bn * BN + wn * 64 + j * 16 + l15;
                    float v = acc[i][j][r] + bv[j] + bf2f(Res[row * NF + col]);
                    v = fmaxf(v, 0.0f);
                    s += v * wv[j];
                }
                s += __shfl_xor(s, 1, 64);
                s += __shfl_xor(s, 2, 64);
                s += __shfl_xor(s, 4, 64);
                s += __shfl_xor(s, 8, 64);
                if (l15 == 0) atomicAdd(outp + row, s + boadd);
            }
        }
    }
}

extern "C" void kernel_launch(void* const* d_in, const int* in_sizes, int n_in,
                              void* d_out, int out_size, void* d_ws, size_t ws_size,
                              hipStream_t stream) {
    (void)in_sizes; (void)n_in; (void)out_size; (void)ws_size;
    const float* latent = (const float*)d_in[0];
    const float* pc     = (const float*)d_in[1];
    const float *wa[3], *ba[3], *wr[3], *br[3], *wo[3], *bo[3];
    for (int s = 0; s < 3; ++s) {
        int base = 2 + s * 6;
        wa[s] = (const float*)d_in[base + 0];
        ba[s] = (const float*)d_in[base + 1];
        wr[s] = (const float*)d_in[base + 2];
        br[s] = (const float*)d_in[base + 3];
        wo[s] = (const float*)d_in[base + 4];
        bo[s] = (const float*)d_in[base + 5];
    }

    char* ws = (char*)d_ws;
    size_t off = 0;
    short* A  = (short*)(ws + off); off += (size_t)M_ROWS * KP_A * 2;   // 35.7 MB
    short* H1 = (short*)(ws + off); off += (size_t)M_ROWS * NF * 2;     // 33.6 MB
    short* Wbase = (short*)(ws + off);
    short *Wta[3], *Wtr[3];
    for (int s = 0; s < 3; ++s) { Wta[s] = Wbase + (size_t)s * NF * KP_A; }
    for (int s = 0; s < 3; ++s) { Wtr[s] = Wbase + (size_t)3 * NF * KP_A + (size_t)s * NF * NF; }
    float* out = (float*)d_out;

    k_latent<<<(M_ROWS * 64) / 256, 256, 0, stream>>>(latent, A);
    dim3 gw((KP_A + 31) / 32, NF / 32, 6);
    k_wt6<<<gw, 256, 0, stream>>>(wa[0], wa[1], wa[2], wr[0], wr[1], wr[2], Wbase);
    k_knncov<<<2048, 256, 0, stream>>>(pc, A);
    k_setbo<<<M_ROWS / 256, 256, 0, stream>>>(out, bo[0], 0);

    int nwg = (M_ROWS / BM) * (NF / BN);   // 512, %8==0
    for (int s = 0; s < 3; ++s) {
        if (s == 0) {
            k_gemm<<<nwg, 512, 0, stream>>>(A, Wta[0], ba[0], nullptr, H1,
                                            nullptr, nullptr, nullptr, nullptr,
                                            nullptr, KP_A, KP_A);
        } else {
            // K=512 + rank-1 (out[row] * wa_row512[col]) in epilogue
            k_gemm<<<nwg, 512, 0, stream>>>(A, Wta[s], ba[s], nullptr, H1,
                                            nullptr, nullptr,
                                            wa[s] + (size_t)NF * NF, out,
                                            nullptr, KP_A, NF);
        }
        k_gemm<<<nwg, 512, 0, stream>>>(H1, Wtr[s], br[s], H1, nullptr,
                                        wo[s], out, nullptr, nullptr,
                                        s > 0 ? bo[s] : nullptr, NF, NF);
    }
}